// Round 1
// baseline (525.479 us; speedup 1.0000x reference)
//
#include <hip/hip_runtime.h>

#define BB   16
#define NN   4096
#define MM   1024
#define CIN  256
#define CSK  128
#define COUT 256
#define KCH  (CIN + CSK)   // 384
#define NP   (BB * NN)     // 65536
#define NSEG 32
#define SEGLEN (NP / NSEG) // 2048

// ---------------------------------------------------------------------------
// K1: KNN (k=3) per point against all 1024 centroids of its batch.
// Positions are the reference's flat-reinterpret: xyz contiguous triples.
// ---------------------------------------------------------------------------
__global__ __launch_bounds__(256) void knn_kernel(
    const float* __restrict__ pts, const float* __restrict__ cen,
    int* __restrict__ knn_idx, float* __restrict__ knn_w)
{
    __shared__ float cxyz[3 * MM];
    __shared__ float cw[MM];

    int p0 = blockIdx.x * 256;     // 16 blocks per batch (N=4096)
    int b  = p0 >> 12;
    const float* cb = cen + (size_t)b * 3 * MM;
    for (int i = threadIdx.x; i < 3 * MM; i += 256) cxyz[i] = cb[i];
    __syncthreads();
    for (int m = threadIdx.x; m < MM; m += 256) {
        float x = cxyz[3*m], y = cxyz[3*m+1], z = cxyz[3*m+2];
        cw[m] = x*x + y*y + z*z;
    }
    __syncthreads();

    int p = p0 + threadIdx.x;
    int n = p & (NN - 1);
    const float* pb = pts + (size_t)b * 3 * NN;
    float px = pb[3*n], py = pb[3*n+1], pz = pb[3*n+2];
    float pw = px*px + py*py + pz*pz;

    float d0 = 1e30f, d1 = 1e30f, d2v = 1e30f;
    int   i0 = 0, i1 = 0, i2 = 0;
    for (int m = 0; m < MM; ++m) {
        float dot = px*cxyz[3*m] + py*cxyz[3*m+1] + pz*cxyz[3*m+2];
        float d = pw + cw[m] - 2.0f * dot;   // same expansion as reference
        if (d < d2v) {
            if (d < d1) {
                if (d < d0) { d2v=d1; i2=i1; d1=d0; i1=i0; d0=d; i0=m; }
                else        { d2v=d1; i2=i1; d1=d;  i1=m; }
            } else          { d2v=d;  i2=m; }
        }
    }
    float w0 = 1.0f / fmaxf(d0,  1e-16f);
    float w1 = 1.0f / fmaxf(d1,  1e-16f);
    float w2 = 1.0f / fmaxf(d2v, 1e-16f);
    float inv = 1.0f / (w0 + w1 + w2);
    knn_idx[3*p] = i0; knn_idx[3*p+1] = i1; knn_idx[3*p+2] = i2;
    knn_w[3*p] = w0*inv; knn_w[3*p+1] = w1*inv; knn_w[3*p+2] = w2*inv;
}

// ---------------------------------------------------------------------------
// K2: interpolation. centroid_features flat-reinterpret = [B][M][CIN] rows.
// Write interp point-major [B][N][CIN] (contiguous per point, coalesced).
// ---------------------------------------------------------------------------
__global__ __launch_bounds__(256) void interp_kernel(
    const float* __restrict__ cf, const int* __restrict__ knn_idx,
    const float* __restrict__ knn_w, float* __restrict__ interp)
{
    int p = blockIdx.x;
    int b = p >> 12;
    int c = threadIdx.x;
    const float* cfb = cf + (size_t)b * MM * CIN;
    int i0 = knn_idx[3*p], i1 = knn_idx[3*p+1], i2 = knn_idx[3*p+2];
    float w0 = knn_w[3*p], w1 = knn_w[3*p+1], w2 = knn_w[3*p+2];
    float v = w0 * cfb[(size_t)i0*CIN + c]
            + w1 * cfb[(size_t)i1*CIN + c]
            + w2 * cfb[(size_t)i2*CIN + c];
    interp[(size_t)p * CIN + c] = v;
}

// ---------------------------------------------------------------------------
// K3: GEMM1  h1[o,p] = sum_c W1[o,c] * H[c,p] + b1[o]
// H rows 0..127 = point_features[b][c][n]; rows 128..383 = interp flat
// reinterpreted as [c*N + n] within each batch block (the .view(B,C,N)).
// 64x64 tile, 16-deep K staging, 4x4 per thread, fp32.
// ---------------------------------------------------------------------------
__global__ __launch_bounds__(256) void gemm1_kernel(
    const float* __restrict__ pf, const float* __restrict__ interp,
    const float* __restrict__ W1, const float* __restrict__ b1,
    float* __restrict__ h1)
{
    __shared__ float As[16][68];  // [k][o_local]
    __shared__ float Bs[16][68];  // [k][p_local]

    int pp0 = blockIdx.x * 64;
    int o0  = blockIdx.y * 64;
    int b   = pp0 >> 12;
    int n0  = pp0 & (NN - 1);
    const float* pfb = pf + (size_t)b * CSK * NN;
    const float* itb = interp + (size_t)b * NN * CIN;  // flat [c*NN + n]

    int tx = threadIdx.x & 15, ty = threadIdx.x >> 4;
    float acc[4][4] = {{0.f}};

    for (int c0 = 0; c0 < KCH; c0 += 16) {
        for (int l = threadIdx.x; l < 1024; l += 256) {
            int r = l >> 4, k = l & 15;
            As[k][r] = W1[(size_t)(o0 + r) * KCH + c0 + k];
        }
        for (int l = threadIdx.x; l < 1024; l += 256) {
            int k = l >> 6, col = l & 63;
            int c = c0 + k;
            Bs[k][col] = (c < CSK) ? pfb[(size_t)c * NN + n0 + col]
                                   : itb[(size_t)(c - CSK) * NN + n0 + col];
        }
        __syncthreads();
        #pragma unroll
        for (int k = 0; k < 16; ++k) {
            float4 av = *(const float4*)&As[k][ty * 4];
            float4 bv = *(const float4*)&Bs[k][tx * 4];
            float a[4] = {av.x, av.y, av.z, av.w};
            float bb[4] = {bv.x, bv.y, bv.z, bv.w};
            #pragma unroll
            for (int i = 0; i < 4; ++i)
                #pragma unroll
                for (int j = 0; j < 4; ++j)
                    acc[i][j] = fmaf(a[i], bb[j], acc[i][j]);
        }
        __syncthreads();
    }
    #pragma unroll
    for (int i = 0; i < 4; ++i) {
        int o = o0 + ty * 4 + i;
        float bias = b1[o];
        float4 v = make_float4(acc[i][0] + bias, acc[i][1] + bias,
                               acc[i][2] + bias, acc[i][3] + bias);
        *(float4*)(h1 + (size_t)o * NP + pp0 + tx * 4) = v;
    }
}

// ---------------------------------------------------------------------------
// K4: per-channel partial sums (deterministic, no atomics)
// ---------------------------------------------------------------------------
__global__ __launch_bounds__(256) void stats_kernel(
    const float* __restrict__ h1, float* __restrict__ psum, float* __restrict__ psq)
{
    __shared__ float ss[256], qq[256];
    int seg = blockIdx.x, o = blockIdx.y;
    const float* row = h1 + (size_t)o * NP + (size_t)seg * SEGLEN;
    float s = 0.f, q = 0.f;
    for (int i = threadIdx.x; i < SEGLEN; i += 256) {
        float v = row[i];
        s += v;
        q = fmaf(v, v, q);
    }
    ss[threadIdx.x] = s; qq[threadIdx.x] = q;
    __syncthreads();
    for (int st = 128; st > 0; st >>= 1) {
        if (threadIdx.x < st) {
            ss[threadIdx.x] += ss[threadIdx.x + st];
            qq[threadIdx.x] += qq[threadIdx.x + st];
        }
        __syncthreads();
    }
    if (threadIdx.x == 0) { psum[o * NSEG + seg] = ss[0]; psq[o * NSEG + seg] = qq[0]; }
}

__global__ __launch_bounds__(256) void bnfin_kernel(
    const float* __restrict__ psum, const float* __restrict__ psq,
    const float* __restrict__ gamma, const float* __restrict__ beta,
    float* __restrict__ bnscale, float* __restrict__ bnshift)
{
    int o = threadIdx.x;
    float S = 0.f, Q = 0.f;
    for (int s = 0; s < NSEG; ++s) { S += psum[o * NSEG + s]; Q += psq[o * NSEG + s]; }
    float mean = S * (1.0f / NP);
    float var  = Q * (1.0f / NP) - mean * mean;   // biased batch var
    float sc = gamma[o] * rsqrtf(var + 1e-5f);
    bnscale[o] = sc;
    bnshift[o] = fmaf(-mean, sc, beta[o]);
}

// ---------------------------------------------------------------------------
// K5: GEMM2 with fused BN-apply + ReLU on the staged operand.
// out[b][o][n] = sum_c W2[o,c] * relu(sc[c]*h1[c,p]+sh[c]) + b2[o]
// ---------------------------------------------------------------------------
__global__ __launch_bounds__(256) void gemm2_kernel(
    const float* __restrict__ h1, const float* __restrict__ W2,
    const float* __restrict__ b2, const float* __restrict__ bnscale,
    const float* __restrict__ bnshift, float* __restrict__ out)
{
    __shared__ float As[16][68];
    __shared__ float Bs[16][68];

    int pp0 = blockIdx.x * 64;
    int o0  = blockIdx.y * 64;
    int tx = threadIdx.x & 15, ty = threadIdx.x >> 4;
    float acc[4][4] = {{0.f}};

    for (int c0 = 0; c0 < COUT; c0 += 16) {
        for (int l = threadIdx.x; l < 1024; l += 256) {
            int r = l >> 4, k = l & 15;
            As[k][r] = W2[(size_t)(o0 + r) * COUT + c0 + k];
        }
        for (int l = threadIdx.x; l < 1024; l += 256) {
            int k = l >> 6, col = l & 63;
            int c = c0 + k;
            float v = h1[(size_t)c * NP + pp0 + col];
            v = fmaf(v, bnscale[c], bnshift[c]);
            Bs[k][col] = fmaxf(v, 0.0f);
        }
        __syncthreads();
        #pragma unroll
        for (int k = 0; k < 16; ++k) {
            float4 av = *(const float4*)&As[k][ty * 4];
            float4 bv = *(const float4*)&Bs[k][tx * 4];
            float a[4] = {av.x, av.y, av.z, av.w};
            float bb[4] = {bv.x, bv.y, bv.z, bv.w};
            #pragma unroll
            for (int i = 0; i < 4; ++i)
                #pragma unroll
                for (int j = 0; j < 4; ++j)
                    acc[i][j] = fmaf(a[i], bb[j], acc[i][j]);
        }
        __syncthreads();
    }
    int b  = pp0 >> 12;
    int n0 = pp0 & (NN - 1);
    #pragma unroll
    for (int i = 0; i < 4; ++i) {
        int o = o0 + ty * 4 + i;
        float bias = b2[o];
        float4 v = make_float4(acc[i][0] + bias, acc[i][1] + bias,
                               acc[i][2] + bias, acc[i][3] + bias);
        *(float4*)(out + ((size_t)b * COUT + o) * NN + n0 + tx * 4) = v;
    }
}

// ---------------------------------------------------------------------------
extern "C" void kernel_launch(void* const* d_in, const int* in_sizes, int n_in,
                              void* d_out, int out_size, void* d_ws, size_t ws_size,
                              hipStream_t stream)
{
    const float* pts   = (const float*)d_in[0];
    const float* pf    = (const float*)d_in[1];
    const float* cen   = (const float*)d_in[2];
    const float* cf    = (const float*)d_in[3];
    const float* W1    = (const float*)d_in[4];
    const float* b1    = (const float*)d_in[5];
    const float* gamma = (const float*)d_in[6];
    const float* beta  = (const float*)d_in[7];
    const float* W2    = (const float*)d_in[8];
    const float* b2    = (const float*)d_in[9];
    float* out = (float*)d_out;

    char* ws = (char*)d_ws;
    size_t off = 0;
    int*   knn_idx = (int*)(ws + off);   off += (size_t)NP * 3 * sizeof(int);
    float* knn_w   = (float*)(ws + off); off += (size_t)NP * 3 * sizeof(float);
    float* interp  = (float*)(ws + off); off += (size_t)NP * CIN * sizeof(float);
    float* h1      = (float*)(ws + off); off += (size_t)COUT * NP * sizeof(float);
    float* psum    = (float*)(ws + off); off += (size_t)COUT * NSEG * sizeof(float);
    float* psq     = (float*)(ws + off); off += (size_t)COUT * NSEG * sizeof(float);
    float* bnscale = (float*)(ws + off); off += (size_t)COUT * sizeof(float);
    float* bnshift = (float*)(ws + off); off += (size_t)COUT * sizeof(float);
    (void)ws_size; (void)in_sizes; (void)n_in; (void)out_size;

    hipLaunchKernelGGL(knn_kernel,    dim3(NP / 256),          dim3(256), 0, stream,
                       pts, cen, knn_idx, knn_w);
    hipLaunchKernelGGL(interp_kernel, dim3(NP),                dim3(256), 0, stream,
                       cf, knn_idx, knn_w, interp);
    hipLaunchKernelGGL(gemm1_kernel,  dim3(NP / 64, COUT / 64), dim3(256), 0, stream,
                       pf, interp, W1, b1, h1);
    hipLaunchKernelGGL(stats_kernel,  dim3(NSEG, COUT),        dim3(256), 0, stream,
                       h1, psum, psq);
    hipLaunchKernelGGL(bnfin_kernel,  dim3(1),                 dim3(256), 0, stream,
                       psum, psq, gamma, beta, bnscale, bnshift);
    hipLaunchKernelGGL(gemm2_kernel,  dim3(NP / 64, COUT / 64), dim3(256), 0, stream,
                       h1, W2, b2, bnscale, bnshift, out);
}

// Round 2
// 257.560 us; speedup vs baseline: 2.0402x; 2.0402x over previous
//
#include <hip/hip_runtime.h>

#define BB   16
#define NN   4096
#define MM   1024
#define CIN  256
#define CSK  128
#define COUT 256
#define KCH  384              // CIN + CSK
#define NP   65536            // BB * NN
#define NSEG 256
#define SEGROWS 256           // NP / NSEG

typedef __attribute__((ext_vector_type(8))) short bf16x8;
typedef __attribute__((ext_vector_type(4))) float f32x4;
typedef __attribute__((ext_vector_type(8))) unsigned short ushort8v;
typedef __attribute__((ext_vector_type(4))) unsigned short ushort4v;

static __device__ __forceinline__ unsigned short f2bf(float f) {
    unsigned u = __builtin_bit_cast(unsigned, f);
    u += 0x7fffu + ((u >> 16) & 1u);          // round-to-nearest-even
    return (unsigned short)(u >> 16);
}
static __device__ __forceinline__ float bf2f(unsigned short h) {
    unsigned u = ((unsigned)h) << 16;
    return __builtin_bit_cast(float, u);
}

// ---------------------------------------------------------------------------
// K1: KNN (k=3). Positions are flat xyz triples (the reference's reinterpret).
// ---------------------------------------------------------------------------
__global__ __launch_bounds__(256) void knn_kernel(
    const float* __restrict__ pts, const float* __restrict__ cen,
    int* __restrict__ knn_idx, float* __restrict__ knn_w)
{
    __shared__ float cxyz[3 * MM];
    __shared__ float cw[MM];

    int p0 = blockIdx.x * 256;
    int b  = p0 >> 12;
    const float* cb = cen + (size_t)b * 3 * MM;
    for (int i = threadIdx.x; i < 3 * MM; i += 256) cxyz[i] = cb[i];
    __syncthreads();
    for (int m = threadIdx.x; m < MM; m += 256) {
        float x = cxyz[3*m], y = cxyz[3*m+1], z = cxyz[3*m+2];
        cw[m] = x*x + y*y + z*z;
    }
    __syncthreads();

    int p = p0 + threadIdx.x;
    int n = p & (NN - 1);
    const float* pb = pts + (size_t)b * 3 * NN;
    float px = pb[3*n], py = pb[3*n+1], pz = pb[3*n+2];
    float pw = px*px + py*py + pz*pz;

    float d0 = 1e30f, d1 = 1e30f, d2v = 1e30f;
    int   i0 = 0, i1 = 0, i2 = 0;
    for (int m = 0; m < MM; ++m) {
        float dot = px*cxyz[3*m] + py*cxyz[3*m+1] + pz*cxyz[3*m+2];
        float d = pw + cw[m] - 2.0f * dot;
        if (d < d2v) {
            if (d < d1) {
                if (d < d0) { d2v=d1; i2=i1; d1=d0; i1=i0; d0=d; i0=m; }
                else        { d2v=d1; i2=i1; d1=d;  i1=m; }
            } else          { d2v=d;  i2=m; }
        }
    }
    float w0 = 1.0f / fmaxf(d0,  1e-16f);
    float w1 = 1.0f / fmaxf(d1,  1e-16f);
    float w2 = 1.0f / fmaxf(d2v, 1e-16f);
    float inv = 1.0f / (w0 + w1 + w2);
    knn_idx[3*p] = i0; knn_idx[3*p+1] = i1; knn_idx[3*p+2] = i2;
    knn_w[3*p] = w0*inv; knn_w[3*p+1] = w1*inv; knn_w[3*p+2] = w2*inv;
}

// ---------------------------------------------------------------------------
// K2: convert W1/W2 to bf16 (tiny)
// ---------------------------------------------------------------------------
__global__ __launch_bounds__(256) void convw_kernel(
    const float* __restrict__ W1, const float* __restrict__ W2,
    unsigned short* __restrict__ W1b, unsigned short* __restrict__ W2b)
{
    int i = blockIdx.x * 256 + threadIdx.x;
    if (i < COUT * KCH) W1b[i] = f2bf(W1[i]);
    else {
        int j = i - COUT * KCH;
        if (j < COUT * COUT) W2b[j] = f2bf(W2[j]);
    }
}

// ---------------------------------------------------------------------------
// K3: pf [b][c][n] fp32  ->  HbT[(b*NN+n)*KCH + c] bf16  (c = 0..127)
// LDS-tiled transpose, 64 n x 128 c per block.
// ---------------------------------------------------------------------------
__global__ __launch_bounds__(256) void pf_t_kernel(
    const float* __restrict__ pf, unsigned short* __restrict__ HbT)
{
    __shared__ float ls[64][129];
    int blk = blockIdx.x;
    int b = blk >> 6, n0 = (blk & 63) * 64;
    int t = threadIdx.x;
    const float* src = pf + (size_t)b * CSK * NN;
    #pragma unroll
    for (int i = 0; i < 32; ++i) {
        int id = t + i * 256;
        int c = id >> 6, nn = id & 63;
        ls[nn][c] = src[(size_t)c * NN + n0 + nn];
    }
    __syncthreads();
    int row = t & 63, ch = (t >> 6) * 32;
    unsigned short* dst = HbT + ((size_t)b * NN + n0 + row) * KCH + ch;
    #pragma unroll
    for (int g = 0; g < 4; ++g) {
        ushort8v w;
        #pragma unroll
        for (int j = 0; j < 8; ++j) w[j] = f2bf(ls[row][ch + g*8 + j]);
        *(ushort8v*)&dst[g*8] = w;
    }
}

// ---------------------------------------------------------------------------
// K4: interp + scramble. The faithful .view gives
//   H_interp(b, cv, n = hi*256 + nlo) = interp(point q = cv*16+hi, chan nlo).
// Block = (b, hi): 256 points q = cv*16+hi, all 256 channels, written as
// HbT rows (n = hi*256 + t), cols 128+cv. cf rows gathered coalesced (L2-hot).
// ---------------------------------------------------------------------------
__global__ __launch_bounds__(256) void interp_kernel(
    const float* __restrict__ cf, const int* __restrict__ knn_idx,
    const float* __restrict__ knn_w, unsigned short* __restrict__ HbT)
{
    __shared__ int   li[256][3];
    __shared__ float lw[256][3];
    __shared__ unsigned short tile[64][258];
    int blk = blockIdx.x;
    int b = blk >> 4, hi = blk & 15;
    int t = threadIdx.x;
    {
        int P = b * NN + t * 16 + hi;
        li[t][0] = knn_idx[3*P];   li[t][1] = knn_idx[3*P+1]; li[t][2] = knn_idx[3*P+2];
        lw[t][0] = knn_w[3*P];     lw[t][1] = knn_w[3*P+1];   lw[t][2] = knn_w[3*P+2];
    }
    __syncthreads();
    const float* cfb = cf + (size_t)b * MM * CIN;
    size_t dstbase = ((size_t)b * NN + hi * 256 + t) * KCH + CSK;
    for (int ch = 0; ch < 4; ++ch) {
        for (int cv = 0; cv < 64; ++cv) {
            int c = ch * 64 + cv;
            float v = lw[c][0] * cfb[(size_t)li[c][0] * CIN + t]
                    + lw[c][1] * cfb[(size_t)li[c][1] * CIN + t]
                    + lw[c][2] * cfb[(size_t)li[c][2] * CIN + t];
            tile[cv][t] = f2bf(v);
        }
        __syncthreads();
        #pragma unroll
        for (int g = 0; g < 8; ++g) {
            ushort8v w;
            #pragma unroll
            for (int j = 0; j < 8; ++j) w[j] = tile[g*8 + j][t];
            *(ushort8v*)&HbT[dstbase + ch*64 + g*8] = w;
        }
        __syncthreads();
    }
}

// ---------------------------------------------------------------------------
// K5: GEMM1 (MFMA bf16): h1T[p][o] = bf16( sum_c W1[o][c]*H[c][p] + b1[o] )
// 128x128 tile, BK=32, 4 waves (2o x 2p), 4x4 16x16x32 frags per wave.
// ---------------------------------------------------------------------------
__global__ __launch_bounds__(256) void gemm1_kernel(
    const unsigned short* __restrict__ HbT, const unsigned short* __restrict__ W1b,
    const float* __restrict__ b1, unsigned short* __restrict__ h1T)
{
    __shared__ __align__(16) unsigned short As[128][40];
    __shared__ __align__(16) unsigned short Bs[128][40];
    int pp0 = blockIdx.x * 128;
    int o0  = blockIdx.y * 128;
    int t = threadIdx.x;
    int wid = t >> 6, lane = t & 63;
    int wr = wid >> 1, wc = wid & 1;
    int lr = lane & 15, lk = lane >> 4;

    f32x4 acc[4][4] = {};

    for (int c0 = 0; c0 < KCH; c0 += 32) {
        #pragma unroll
        for (int i = 0; i < 2; ++i) {
            int id = t + i * 256;
            int row = id >> 2, q = id & 3;
            *(ushort8v*)&As[row][q*8] =
                *(const ushort8v*)&W1b[(size_t)(o0 + row) * KCH + c0 + q*8];
            *(ushort8v*)&Bs[row][q*8] =
                *(const ushort8v*)&HbT[(size_t)(pp0 + row) * KCH + c0 + q*8];
        }
        __syncthreads();
        bf16x8 af[4], bfr[4];
        #pragma unroll
        for (int m = 0; m < 4; ++m) af[m] = *(const bf16x8*)&As[wr*64 + m*16 + lr][lk*8];
        #pragma unroll
        for (int n = 0; n < 4; ++n) bfr[n] = *(const bf16x8*)&Bs[wc*64 + n*16 + lr][lk*8];
        #pragma unroll
        for (int m = 0; m < 4; ++m)
            #pragma unroll
            for (int n = 0; n < 4; ++n)
                acc[m][n] = __builtin_amdgcn_mfma_f32_16x16x32_bf16(af[m], bfr[n], acc[m][n], 0, 0, 0);
        __syncthreads();
    }
    #pragma unroll
    for (int n = 0; n < 4; ++n) {
        int p = pp0 + wc*64 + n*16 + lr;
        #pragma unroll
        for (int m = 0; m < 4; ++m) {
            int o = o0 + wr*64 + m*16 + lk*4;
            f32x4 v = acc[m][n];
            ushort4v w;
            w[0] = f2bf(v[0] + b1[o]);
            w[1] = f2bf(v[1] + b1[o+1]);
            w[2] = f2bf(v[2] + b1[o+2]);
            w[3] = f2bf(v[3] + b1[o+3]);
            *(ushort4v*)&h1T[(size_t)p * COUT + o] = w;
        }
    }
}

// ---------------------------------------------------------------------------
// K6: per-channel partial sums over h1T (columnar, coalesced, deterministic)
// ---------------------------------------------------------------------------
__global__ __launch_bounds__(256) void stats_kernel(
    const unsigned short* __restrict__ h1T, float* __restrict__ psum, float* __restrict__ psq)
{
    __shared__ float ls[256][8];
    int seg = blockIdx.x, t = threadIdx.x;
    int col8 = (t & 31) * 8, rg = t >> 5;
    float s[8] = {}, q[8] = {};
    size_t base = (size_t)seg * SEGROWS * COUT;
    for (int p = rg; p < SEGROWS; p += 8) {
        ushort8v v = *(const ushort8v*)&h1T[base + (size_t)p * COUT + col8];
        #pragma unroll
        for (int j = 0; j < 8; ++j) { float f = bf2f(v[j]); s[j] += f; q[j] = fmaf(f, f, q[j]); }
    }
    #pragma unroll
    for (int j = 0; j < 8; ++j) ls[t][j] = s[j];
    __syncthreads();
    for (int off = 128; off >= 32; off >>= 1) {
        if (t < off) {
            #pragma unroll
            for (int j = 0; j < 8; ++j) ls[t][j] += ls[t + off][j];
        }
        __syncthreads();
    }
    if (t < 32) {
        #pragma unroll
        for (int j = 0; j < 8; ++j) psum[seg * COUT + t*8 + j] = ls[t][j];
    }
    __syncthreads();
    #pragma unroll
    for (int j = 0; j < 8; ++j) ls[t][j] = q[j];
    __syncthreads();
    for (int off = 128; off >= 32; off >>= 1) {
        if (t < off) {
            #pragma unroll
            for (int j = 0; j < 8; ++j) ls[t][j] += ls[t + off][j];
        }
        __syncthreads();
    }
    if (t < 32) {
        #pragma unroll
        for (int j = 0; j < 8; ++j) psq[seg * COUT + t*8 + j] = ls[t][j];
    }
}

__global__ __launch_bounds__(256) void bnfin_kernel(
    const float* __restrict__ psum, const float* __restrict__ psq,
    const float* __restrict__ gamma, const float* __restrict__ beta,
    float* __restrict__ bnscale, float* __restrict__ bnshift)
{
    int o = threadIdx.x;
    float S = 0.f, Q = 0.f;
    for (int s = 0; s < NSEG; ++s) { S += psum[s * COUT + o]; Q += psq[s * COUT + o]; }
    float mean = S * (1.0f / NP);
    float var  = Q * (1.0f / NP) - mean * mean;
    float sc = gamma[o] * rsqrtf(var + 1e-5f);
    bnscale[o] = sc;
    bnshift[o] = fmaf(-mean, sc, beta[o]);
}

// ---------------------------------------------------------------------------
// K7: GEMM2 (MFMA bf16) with BN+ReLU fused into B-staging.
// out[b][o2][n] = sum_o W2[o2][o] * relu(sc[o]*h1T[p][o]+sh[o]) + b2[o2]
// ---------------------------------------------------------------------------
__global__ __launch_bounds__(256) void gemm2_kernel(
    const unsigned short* __restrict__ h1T, const unsigned short* __restrict__ W2b,
    const float* __restrict__ b2, const float* __restrict__ bnscale,
    const float* __restrict__ bnshift, float* __restrict__ out)
{
    __shared__ __align__(16) unsigned short As[128][40];
    __shared__ __align__(16) unsigned short Bs[128][40];
    __shared__ float scs[COUT], shs[COUT];
    int pp0 = blockIdx.x * 128;
    int o0  = blockIdx.y * 128;
    int t = threadIdx.x;
    scs[t] = bnscale[t]; shs[t] = bnshift[t];
    int wid = t >> 6, lane = t & 63;
    int wr = wid >> 1, wc = wid & 1;
    int lr = lane & 15, lk = lane >> 4;
    f32x4 acc[4][4] = {};
    __syncthreads();

    for (int c0 = 0; c0 < COUT; c0 += 32) {
        #pragma unroll
        for (int i = 0; i < 2; ++i) {
            int id = t + i * 256;
            int row = id >> 2, q = id & 3;
            *(ushort8v*)&As[row][q*8] =
                *(const ushort8v*)&W2b[(size_t)(o0 + row) * COUT + c0 + q*8];
            ushort8v hv = *(const ushort8v*)&h1T[(size_t)(pp0 + row) * COUT + c0 + q*8];
            ushort8v bv;
            #pragma unroll
            for (int j = 0; j < 8; ++j) {
                float f = fmaf(bf2f(hv[j]), scs[c0 + q*8 + j], shs[c0 + q*8 + j]);
                bv[j] = f2bf(fmaxf(f, 0.0f));
            }
            *(ushort8v*)&Bs[row][q*8] = bv;
        }
        __syncthreads();
        bf16x8 af[4], bfr[4];
        #pragma unroll
        for (int m = 0; m < 4; ++m) af[m] = *(const bf16x8*)&As[wr*64 + m*16 + lr][lk*8];
        #pragma unroll
        for (int n = 0; n < 4; ++n) bfr[n] = *(const bf16x8*)&Bs[wc*64 + n*16 + lr][lk*8];
        #pragma unroll
        for (int m = 0; m < 4; ++m)
            #pragma unroll
            for (int n = 0; n < 4; ++n)
                acc[m][n] = __builtin_amdgcn_mfma_f32_16x16x32_bf16(af[m], bfr[n], acc[m][n], 0, 0, 0);
        __syncthreads();
    }
    #pragma unroll
    for (int n = 0; n < 4; ++n) {
        int p = pp0 + wc*64 + n*16 + lr;
        int b = p >> 12, nn = p & (NN - 1);
        #pragma unroll
        for (int m = 0; m < 4; ++m) {
            int o = o0 + wr*64 + m*16 + lk*4;
            f32x4 v = acc[m][n];
            float* dst = out + ((size_t)(b * COUT + o)) * NN + nn;
            dst[0]        = v[0] + b2[o];
            dst[NN]       = v[1] + b2[o+1];
            dst[2*NN]     = v[2] + b2[o+2];
            dst[3*NN]     = v[3] + b2[o+3];
        }
    }
}

// ---------------------------------------------------------------------------
extern "C" void kernel_launch(void* const* d_in, const int* in_sizes, int n_in,
                              void* d_out, int out_size, void* d_ws, size_t ws_size,
                              hipStream_t stream)
{
    const float* pts   = (const float*)d_in[0];
    const float* pf    = (const float*)d_in[1];
    const float* cen   = (const float*)d_in[2];
    const float* cf    = (const float*)d_in[3];
    const float* W1    = (const float*)d_in[4];
    const float* b1    = (const float*)d_in[5];
    const float* gamma = (const float*)d_in[6];
    const float* beta  = (const float*)d_in[7];
    const float* W2    = (const float*)d_in[8];
    const float* b2    = (const float*)d_in[9];
    float* out = (float*)d_out;

    char* ws = (char*)d_ws;
    size_t off = 0;
    unsigned short* HbT = (unsigned short*)(ws + off); off += (size_t)NP * KCH * 2;
    unsigned short* h1T = (unsigned short*)(ws + off); off += (size_t)NP * COUT * 2;
    unsigned short* W1b = (unsigned short*)(ws + off); off += (size_t)COUT * KCH * 2;
    unsigned short* W2b = (unsigned short*)(ws + off); off += (size_t)COUT * COUT * 2;
    int*   knn_idx = (int*)(ws + off);   off += (size_t)NP * 3 * sizeof(int);
    float* knn_w   = (float*)(ws + off); off += (size_t)NP * 3 * sizeof(float);
    float* psum    = (float*)(ws + off); off += (size_t)NSEG * COUT * sizeof(float);
    float* psq     = (float*)(ws + off); off += (size_t)NSEG * COUT * sizeof(float);
    float* bnscale = (float*)(ws + off); off += 1024;
    float* bnshift = (float*)(ws + off); off += 1024;
    (void)ws_size; (void)in_sizes; (void)n_in; (void)out_size;

    hipLaunchKernelGGL(convw_kernel,  dim3(640),            dim3(256), 0, stream,
                       W1, W2, W1b, W2b);
    hipLaunchKernelGGL(knn_kernel,    dim3(NP / 256),       dim3(256), 0, stream,
                       pts, cen, knn_idx, knn_w);
    hipLaunchKernelGGL(pf_t_kernel,   dim3(BB * 64),        dim3(256), 0, stream,
                       pf, HbT);
    hipLaunchKernelGGL(interp_kernel, dim3(BB * 16),        dim3(256), 0, stream,
                       cf, knn_idx, knn_w, HbT);
    hipLaunchKernelGGL(gemm1_kernel,  dim3(NP / 128, 2),    dim3(256), 0, stream,
                       HbT, W1b, b1, h1T);
    hipLaunchKernelGGL(stats_kernel,  dim3(NSEG),           dim3(256), 0, stream,
                       h1T, psum, psq);
    hipLaunchKernelGGL(bnfin_kernel,  dim3(1),              dim3(256), 0, stream,
                       psum, psq, gamma, beta, bnscale, bnshift);
    hipLaunchKernelGGL(gemm2_kernel,  dim3(NP / 128, 2),    dim3(256), 0, stream,
                       h1T, W2b, b2, bnscale, bnshift, out);
}

// Round 3
// 197.517 us; speedup vs baseline: 2.6604x; 1.3040x over previous
//
#include <hip/hip_runtime.h>

#define BB   16
#define NN   4096
#define MM   1024
#define CIN  256
#define CSK  128
#define COUT 256
#define KCH  384              // CIN + CSK
#define NP   65536            // BB * NN
#define NSEG 256
#define SEGROWS 256           // NP / NSEG
#define NCHUNK 4
#define MCH  (MM / NCHUNK)    // 256

typedef __attribute__((ext_vector_type(8))) short bf16x8;
typedef __attribute__((ext_vector_type(4))) float f32x4;
typedef __attribute__((ext_vector_type(8))) unsigned short ushort8v;
typedef __attribute__((ext_vector_type(4))) unsigned short ushort4v;

static __device__ __forceinline__ unsigned short f2bf(float f) {
    unsigned u = __builtin_bit_cast(unsigned, f);
    u += 0x7fffu + ((u >> 16) & 1u);          // round-to-nearest-even
    return (unsigned short)(u >> 16);
}
static __device__ __forceinline__ float bf2f(unsigned short h) {
    unsigned u = ((unsigned)h) << 16;
    return __builtin_bit_cast(float, u);
}

// ---------------------------------------------------------------------------
// K1a: partial KNN — each block handles 256 points x 256 centroids (1 chunk).
// Grid (NP/256, NCHUNK) -> 1024 blocks -> ~16 waves/CU.
// ---------------------------------------------------------------------------
__global__ __launch_bounds__(256) void knn_part_kernel(
    const float* __restrict__ pts, const float* __restrict__ cen,
    float* __restrict__ pdist, int* __restrict__ pidx)
{
    __shared__ float tmp[3 * MCH];
    __shared__ float sx[MCH], sy[MCH], sz[MCH], sw[MCH];

    int p0    = blockIdx.x * 256;
    int chunk = blockIdx.y;
    int b     = p0 >> 12;
    int m0    = chunk * MCH;
    const float* cb = cen + (size_t)b * 3 * MM + 3 * m0;
    for (int i = threadIdx.x; i < 3 * MCH; i += 256) tmp[i] = cb[i];
    __syncthreads();
    {
        int m = threadIdx.x;
        float x = tmp[3*m], y = tmp[3*m+1], z = tmp[3*m+2];
        sx[m] = x; sy[m] = y; sz[m] = z;
        sw[m] = x*x + y*y + z*z;
    }
    __syncthreads();

    int p = p0 + threadIdx.x;
    int n = p & (NN - 1);
    const float* pb = pts + (size_t)b * 3 * NN;
    float px = pb[3*n], py = pb[3*n+1], pz = pb[3*n+2];
    float pw = px*px + py*py + pz*pz;

    float d0 = 1e30f, d1 = 1e30f, d2v = 1e30f;
    int   i0 = 0, i1 = 0, i2 = 0;
    #pragma unroll 8
    for (int m = 0; m < MCH; ++m) {
        float dot = px*sx[m] + py*sy[m] + pz*sz[m];
        float d = pw + sw[m] - 2.0f * dot;    // same expansion as reference
        if (d < d2v) {
            if (d < d1) {
                if (d < d0) { d2v=d1; i2=i1; d1=d0; i1=i0; d0=d; i0=m; }
                else        { d2v=d1; i2=i1; d1=d;  i1=m; }
            } else          { d2v=d;  i2=m; }
        }
    }
    int base = (p * NCHUNK + chunk) * 3;
    pdist[base] = d0;      pdist[base+1] = d1;      pdist[base+2] = d2v;
    pidx[base]  = m0 + i0; pidx[base+1]  = m0 + i1; pidx[base+2]  = m0 + i2;
}

// ---------------------------------------------------------------------------
// K1b: merge 4 sorted top-3 partials per point (chunk-major, strict < keeps
// the reference's lowest-index-on-tie order).
// ---------------------------------------------------------------------------
__global__ __launch_bounds__(256) void knn_merge_kernel(
    const float* __restrict__ pdist, const int* __restrict__ pidx,
    int* __restrict__ knn_idx, float* __restrict__ knn_w)
{
    int p = blockIdx.x * 256 + threadIdx.x;
    float d0 = 1e30f, d1 = 1e30f, d2v = 1e30f;
    int   i0 = 0, i1 = 0, i2 = 0;
    int base = p * NCHUNK * 3;
    #pragma unroll
    for (int c = 0; c < NCHUNK * 3; ++c) {
        float d = pdist[base + c];
        int   i = pidx[base + c];
        if (d < d2v) {
            if (d < d1) {
                if (d < d0) { d2v=d1; i2=i1; d1=d0; i1=i0; d0=d; i0=i; }
                else        { d2v=d1; i2=i1; d1=d;  i1=i; }
            } else          { d2v=d;  i2=i; }
        }
    }
    float w0 = 1.0f / fmaxf(d0,  1e-16f);
    float w1 = 1.0f / fmaxf(d1,  1e-16f);
    float w2 = 1.0f / fmaxf(d2v, 1e-16f);
    float inv = 1.0f / (w0 + w1 + w2);
    knn_idx[3*p] = i0; knn_idx[3*p+1] = i1; knn_idx[3*p+2] = i2;
    knn_w[3*p] = w0*inv; knn_w[3*p+1] = w1*inv; knn_w[3*p+2] = w2*inv;
}

// ---------------------------------------------------------------------------
// K2: convert W1/W2 to bf16 (tiny)
// ---------------------------------------------------------------------------
__global__ __launch_bounds__(256) void convw_kernel(
    const float* __restrict__ W1, const float* __restrict__ W2,
    unsigned short* __restrict__ W1b, unsigned short* __restrict__ W2b)
{
    int i = blockIdx.x * 256 + threadIdx.x;
    if (i < COUT * KCH) W1b[i] = f2bf(W1[i]);
    else {
        int j = i - COUT * KCH;
        if (j < COUT * COUT) W2b[j] = f2bf(W2[j]);
    }
}

// ---------------------------------------------------------------------------
// K3: pf [b][c][n] fp32  ->  HbT[(b*NN+n)*KCH + c] bf16  (c = 0..127)
// ---------------------------------------------------------------------------
__global__ __launch_bounds__(256) void pf_t_kernel(
    const float* __restrict__ pf, unsigned short* __restrict__ HbT)
{
    __shared__ float ls[64][129];
    int blk = blockIdx.x;
    int b = blk >> 6, n0 = (blk & 63) * 64;
    int t = threadIdx.x;
    const float* src = pf + (size_t)b * CSK * NN;
    #pragma unroll
    for (int i = 0; i < 32; ++i) {
        int id = t + i * 256;
        int c = id >> 6, nn = id & 63;
        ls[nn][c] = src[(size_t)c * NN + n0 + nn];
    }
    __syncthreads();
    int row = t & 63, ch = (t >> 6) * 32;
    unsigned short* dst = HbT + ((size_t)b * NN + n0 + row) * KCH + ch;
    #pragma unroll
    for (int g = 0; g < 4; ++g) {
        ushort8v w;
        #pragma unroll
        for (int j = 0; j < 8; ++j) w[j] = f2bf(ls[row][ch + g*8 + j]);
        *(ushort8v*)&dst[g*8] = w;
    }
}

// ---------------------------------------------------------------------------
// K4: interp + scramble. H_interp(b, cv, n=hi*256+nlo) = interp(q=cv*16+hi, nlo)
// ---------------------------------------------------------------------------
__global__ __launch_bounds__(256) void interp_kernel(
    const float* __restrict__ cf, const int* __restrict__ knn_idx,
    const float* __restrict__ knn_w, unsigned short* __restrict__ HbT)
{
    __shared__ int   li[256][3];
    __shared__ float lw[256][3];
    __shared__ unsigned short tile[64][258];
    int blk = blockIdx.x;
    int b = blk >> 4, hi = blk & 15;
    int t = threadIdx.x;
    {
        int P = b * NN + t * 16 + hi;
        li[t][0] = knn_idx[3*P];   li[t][1] = knn_idx[3*P+1]; li[t][2] = knn_idx[3*P+2];
        lw[t][0] = knn_w[3*P];     lw[t][1] = knn_w[3*P+1];   lw[t][2] = knn_w[3*P+2];
    }
    __syncthreads();
    const float* cfb = cf + (size_t)b * MM * CIN;
    size_t dstbase = ((size_t)b * NN + hi * 256 + t) * KCH + CSK;
    for (int ch = 0; ch < 4; ++ch) {
        for (int cv = 0; cv < 64; ++cv) {
            int c = ch * 64 + cv;
            float v = lw[c][0] * cfb[(size_t)li[c][0] * CIN + t]
                    + lw[c][1] * cfb[(size_t)li[c][1] * CIN + t]
                    + lw[c][2] * cfb[(size_t)li[c][2] * CIN + t];
            tile[cv][t] = f2bf(v);
        }
        __syncthreads();
        #pragma unroll
        for (int g = 0; g < 8; ++g) {
            ushort8v w;
            #pragma unroll
            for (int j = 0; j < 8; ++j) w[j] = tile[g*8 + j][t];
            *(ushort8v*)&HbT[dstbase + ch*64 + g*8] = w;
        }
        __syncthreads();
    }
}

// ---------------------------------------------------------------------------
// K5: GEMM1 (MFMA bf16): h1T[p][o] = bf16( sum_c W1[o][c]*H[c][p] + b1[o] )
// ---------------------------------------------------------------------------
__global__ __launch_bounds__(256) void gemm1_kernel(
    const unsigned short* __restrict__ HbT, const unsigned short* __restrict__ W1b,
    const float* __restrict__ b1, unsigned short* __restrict__ h1T)
{
    __shared__ __align__(16) unsigned short As[128][40];
    __shared__ __align__(16) unsigned short Bs[128][40];
    int pp0 = blockIdx.x * 128;
    int o0  = blockIdx.y * 128;
    int t = threadIdx.x;
    int wid = t >> 6, lane = t & 63;
    int wr = wid >> 1, wc = wid & 1;
    int lr = lane & 15, lk = lane >> 4;

    f32x4 acc[4][4] = {};

    for (int c0 = 0; c0 < KCH; c0 += 32) {
        #pragma unroll
        for (int i = 0; i < 2; ++i) {
            int id = t + i * 256;
            int row = id >> 2, q = id & 3;
            *(ushort8v*)&As[row][q*8] =
                *(const ushort8v*)&W1b[(size_t)(o0 + row) * KCH + c0 + q*8];
            *(ushort8v*)&Bs[row][q*8] =
                *(const ushort8v*)&HbT[(size_t)(pp0 + row) * KCH + c0 + q*8];
        }
        __syncthreads();
        bf16x8 af[4], bfr[4];
        #pragma unroll
        for (int m = 0; m < 4; ++m) af[m] = *(const bf16x8*)&As[wr*64 + m*16 + lr][lk*8];
        #pragma unroll
        for (int n = 0; n < 4; ++n) bfr[n] = *(const bf16x8*)&Bs[wc*64 + n*16 + lr][lk*8];
        #pragma unroll
        for (int m = 0; m < 4; ++m)
            #pragma unroll
            for (int n = 0; n < 4; ++n)
                acc[m][n] = __builtin_amdgcn_mfma_f32_16x16x32_bf16(af[m], bfr[n], acc[m][n], 0, 0, 0);
        __syncthreads();
    }
    #pragma unroll
    for (int n = 0; n < 4; ++n) {
        int p = pp0 + wc*64 + n*16 + lr;
        #pragma unroll
        for (int m = 0; m < 4; ++m) {
            int o = o0 + wr*64 + m*16 + lk*4;
            f32x4 v = acc[m][n];
            ushort4v w;
            w[0] = f2bf(v[0] + b1[o]);
            w[1] = f2bf(v[1] + b1[o+1]);
            w[2] = f2bf(v[2] + b1[o+2]);
            w[3] = f2bf(v[3] + b1[o+3]);
            *(ushort4v*)&h1T[(size_t)p * COUT + o] = w;
        }
    }
}

// ---------------------------------------------------------------------------
// K6: per-channel partial sums over h1T (columnar, coalesced, deterministic)
// ---------------------------------------------------------------------------
__global__ __launch_bounds__(256) void stats_kernel(
    const unsigned short* __restrict__ h1T, float* __restrict__ psum, float* __restrict__ psq)
{
    __shared__ float ls[256][8];
    int seg = blockIdx.x, t = threadIdx.x;
    int col8 = (t & 31) * 8, rg = t >> 5;
    float s[8] = {}, q[8] = {};
    size_t base = (size_t)seg * SEGROWS * COUT;
    for (int p = rg; p < SEGROWS; p += 8) {
        ushort8v v = *(const ushort8v*)&h1T[base + (size_t)p * COUT + col8];
        #pragma unroll
        for (int j = 0; j < 8; ++j) { float f = bf2f(v[j]); s[j] += f; q[j] = fmaf(f, f, q[j]); }
    }
    #pragma unroll
    for (int j = 0; j < 8; ++j) ls[t][j] = s[j];
    __syncthreads();
    for (int off = 128; off >= 32; off >>= 1) {
        if (t < off) {
            #pragma unroll
            for (int j = 0; j < 8; ++j) ls[t][j] += ls[t + off][j];
        }
        __syncthreads();
    }
    if (t < 32) {
        #pragma unroll
        for (int j = 0; j < 8; ++j) psum[seg * COUT + t*8 + j] = ls[t][j];
    }
    __syncthreads();
    #pragma unroll
    for (int j = 0; j < 8; ++j) ls[t][j] = q[j];
    __syncthreads();
    for (int off = 128; off >= 32; off >>= 1) {
        if (t < off) {
            #pragma unroll
            for (int j = 0; j < 8; ++j) ls[t][j] += ls[t + off][j];
        }
        __syncthreads();
    }
    if (t < 32) {
        #pragma unroll
        for (int j = 0; j < 8; ++j) psq[seg * COUT + t*8 + j] = ls[t][j];
    }
}

__global__ __launch_bounds__(256) void bnfin_kernel(
    const float* __restrict__ psum, const float* __restrict__ psq,
    const float* __restrict__ gamma, const float* __restrict__ beta,
    float* __restrict__ bnscale, float* __restrict__ bnshift)
{
    int o = threadIdx.x;
    float S = 0.f, Q = 0.f;
    for (int s = 0; s < NSEG; ++s) { S += psum[s * COUT + o]; Q += psq[s * COUT + o]; }
    float mean = S * (1.0f / NP);
    float var  = Q * (1.0f / NP) - mean * mean;
    float sc = gamma[o] * rsqrtf(var + 1e-5f);
    bnscale[o] = sc;
    bnshift[o] = fmaf(-mean, sc, beta[o]);
}

// ---------------------------------------------------------------------------
// K7: GEMM2 (MFMA bf16) with BN+ReLU fused into B-staging.
// ---------------------------------------------------------------------------
__global__ __launch_bounds__(256) void gemm2_kernel(
    const unsigned short* __restrict__ h1T, const unsigned short* __restrict__ W2b,
    const float* __restrict__ b2, const float* __restrict__ bnscale,
    const float* __restrict__ bnshift, float* __restrict__ out)
{
    __shared__ __align__(16) unsigned short As[128][40];
    __shared__ __align__(16) unsigned short Bs[128][40];
    __shared__ float scs[COUT], shs[COUT];
    int pp0 = blockIdx.x * 128;
    int o0  = blockIdx.y * 128;
    int t = threadIdx.x;
    scs[t] = bnscale[t]; shs[t] = bnshift[t];
    int wid = t >> 6, lane = t & 63;
    int wr = wid >> 1, wc = wid & 1;
    int lr = lane & 15, lk = lane >> 4;
    f32x4 acc[4][4] = {};
    __syncthreads();

    for (int c0 = 0; c0 < COUT; c0 += 32) {
        #pragma unroll
        for (int i = 0; i < 2; ++i) {
            int id = t + i * 256;
            int row = id >> 2, q = id & 3;
            *(ushort8v*)&As[row][q*8] =
                *(const ushort8v*)&W2b[(size_t)(o0 + row) * COUT + c0 + q*8];
            ushort8v hv = *(const ushort8v*)&h1T[(size_t)(pp0 + row) * COUT + c0 + q*8];
            ushort8v bv;
            #pragma unroll
            for (int j = 0; j < 8; ++j) {
                float f = fmaf(bf2f(hv[j]), scs[c0 + q*8 + j], shs[c0 + q*8 + j]);
                bv[j] = f2bf(fmaxf(f, 0.0f));
            }
            *(ushort8v*)&Bs[row][q*8] = bv;
        }
        __syncthreads();
        bf16x8 af[4], bfr[4];
        #pragma unroll
        for (int m = 0; m < 4; ++m) af[m] = *(const bf16x8*)&As[wr*64 + m*16 + lr][lk*8];
        #pragma unroll
        for (int n = 0; n < 4; ++n) bfr[n] = *(const bf16x8*)&Bs[wc*64 + n*16 + lr][lk*8];
        #pragma unroll
        for (int m = 0; m < 4; ++m)
            #pragma unroll
            for (int n = 0; n < 4; ++n)
                acc[m][n] = __builtin_amdgcn_mfma_f32_16x16x32_bf16(af[m], bfr[n], acc[m][n], 0, 0, 0);
        __syncthreads();
    }
    #pragma unroll
    for (int n = 0; n < 4; ++n) {
        int p = pp0 + wc*64 + n*16 + lr;
        int b = p >> 12, nn = p & (NN - 1);
        #pragma unroll
        for (int m = 0; m < 4; ++m) {
            int o = o0 + wr*64 + m*16 + lk*4;
            f32x4 v = acc[m][n];
            float* dst = out + ((size_t)(b * COUT + o)) * NN + nn;
            dst[0]        = v[0] + b2[o];
            dst[NN]       = v[1] + b2[o+1];
            dst[2*NN]     = v[2] + b2[o+2];
            dst[3*NN]     = v[3] + b2[o+3];
        }
    }
}

// ---------------------------------------------------------------------------
extern "C" void kernel_launch(void* const* d_in, const int* in_sizes, int n_in,
                              void* d_out, int out_size, void* d_ws, size_t ws_size,
                              hipStream_t stream)
{
    const float* pts   = (const float*)d_in[0];
    const float* pf    = (const float*)d_in[1];
    const float* cen   = (const float*)d_in[2];
    const float* cf    = (const float*)d_in[3];
    const float* W1    = (const float*)d_in[4];
    const float* b1    = (const float*)d_in[5];
    const float* gamma = (const float*)d_in[6];
    const float* beta  = (const float*)d_in[7];
    const float* W2    = (const float*)d_in[8];
    const float* b2    = (const float*)d_in[9];
    float* out = (float*)d_out;

    char* ws = (char*)d_ws;
    size_t off = 0;
    unsigned short* HbT = (unsigned short*)(ws + off); off += (size_t)NP * KCH * 2;
    unsigned short* h1T = (unsigned short*)(ws + off); off += (size_t)NP * COUT * 2;
    unsigned short* W1b = (unsigned short*)(ws + off); off += (size_t)COUT * KCH * 2;
    unsigned short* W2b = (unsigned short*)(ws + off); off += (size_t)COUT * COUT * 2;
    int*   knn_idx = (int*)(ws + off);   off += (size_t)NP * 3 * sizeof(int);
    float* knn_w   = (float*)(ws + off); off += (size_t)NP * 3 * sizeof(float);
    float* pdist   = (float*)(ws + off); off += (size_t)NP * NCHUNK * 3 * sizeof(float);
    int*   pidx    = (int*)(ws + off);   off += (size_t)NP * NCHUNK * 3 * sizeof(int);
    float* psum    = (float*)(ws + off); off += (size_t)NSEG * COUT * sizeof(float);
    float* psq     = (float*)(ws + off); off += (size_t)NSEG * COUT * sizeof(float);
    float* bnscale = (float*)(ws + off); off += 1024;
    float* bnshift = (float*)(ws + off); off += 1024;
    (void)ws_size; (void)in_sizes; (void)n_in; (void)out_size;

    hipLaunchKernelGGL(convw_kernel,    dim3(640),               dim3(256), 0, stream,
                       W1, W2, W1b, W2b);
    hipLaunchKernelGGL(knn_part_kernel, dim3(NP / 256, NCHUNK),  dim3(256), 0, stream,
                       pts, cen, pdist, pidx);
    hipLaunchKernelGGL(knn_merge_kernel, dim3(NP / 256),         dim3(256), 0, stream,
                       pdist, pidx, knn_idx, knn_w);
    hipLaunchKernelGGL(pf_t_kernel,     dim3(BB * 64),           dim3(256), 0, stream,
                       pf, HbT);
    hipLaunchKernelGGL(interp_kernel,   dim3(BB * 16),           dim3(256), 0, stream,
                       cf, knn_idx, knn_w, HbT);
    hipLaunchKernelGGL(gemm1_kernel,    dim3(NP / 128, 2),       dim3(256), 0, stream,
                       HbT, W1b, b1, h1T);
    hipLaunchKernelGGL(stats_kernel,    dim3(NSEG),              dim3(256), 0, stream,
                       h1T, psum, psq);
    hipLaunchKernelGGL(bnfin_kernel,    dim3(1),                 dim3(256), 0, stream,
                       psum, psq, gamma, beta, bnscale, bnshift);
    hipLaunchKernelGGL(gemm2_kernel,    dim3(NP / 128, 2),       dim3(256), 0, stream,
                       h1T, W2b, b2, bnscale, bnshift, out);
}

// Round 4
// 186.536 us; speedup vs baseline: 2.8170x; 1.0589x over previous
//
#include <hip/hip_runtime.h>

#define BB   16
#define NN   4096
#define MM   1024
#define CIN  256
#define CSK  128
#define COUT 256
#define KCH  384              // CIN + CSK
#define NP   65536            // BB * NN
#define NSEG 256
#define SEGROWS 256           // NP / NSEG
#define NCHUNK 8
#define MCH  (MM / NCHUNK)    // 128
#define CVB  32               // interp channel-slots per block

typedef __attribute__((ext_vector_type(8))) short bf16x8;
typedef __attribute__((ext_vector_type(4))) float f32x4;
typedef __attribute__((ext_vector_type(8))) unsigned short ushort8v;
typedef __attribute__((ext_vector_type(4))) unsigned short ushort4v;

static __device__ __forceinline__ unsigned short f2bf(float f) {
    unsigned u = __builtin_bit_cast(unsigned, f);
    u += 0x7fffu + ((u >> 16) & 1u);          // round-to-nearest-even
    return (unsigned short)(u >> 16);
}
static __device__ __forceinline__ float bf2f(unsigned short h) {
    unsigned u = ((unsigned)h) << 16;
    return __builtin_bit_cast(float, u);
}

// ---------------------------------------------------------------------------
// K1a: partial KNN — 256 points x 128 centroids per block.
// Grid (NP/256, NCHUNK=8) = 2048 blocks -> 8 blocks/CU -> 32 waves/CU.
// ---------------------------------------------------------------------------
__global__ __launch_bounds__(256) void knn_part_kernel(
    const float* __restrict__ pts, const float* __restrict__ cen,
    float* __restrict__ pdist, int* __restrict__ pidx)
{
    __shared__ float tmp[3 * MCH];
    __shared__ float sx[MCH], sy[MCH], sz[MCH], sw[MCH];

    int p0    = blockIdx.x * 256;
    int chunk = blockIdx.y;
    int b     = p0 >> 12;
    int m0    = chunk * MCH;
    const float* cb = cen + (size_t)b * 3 * MM + 3 * m0;
    for (int i = threadIdx.x; i < 3 * MCH; i += 256) tmp[i] = cb[i];
    __syncthreads();
    if (threadIdx.x < MCH) {
        int m = threadIdx.x;
        float x = tmp[3*m], y = tmp[3*m+1], z = tmp[3*m+2];
        sx[m] = x; sy[m] = y; sz[m] = z;
        sw[m] = x*x + y*y + z*z;
    }
    __syncthreads();

    int p = p0 + threadIdx.x;
    int n = p & (NN - 1);
    const float* pb = pts + (size_t)b * 3 * NN;
    float px = pb[3*n], py = pb[3*n+1], pz = pb[3*n+2];
    float pw = px*px + py*py + pz*pz;

    float d0 = 1e30f, d1 = 1e30f, d2v = 1e30f;
    int   i0 = 0, i1 = 0, i2 = 0;
    #pragma unroll 8
    for (int m = 0; m < MCH; ++m) {
        float dot = px*sx[m] + py*sy[m] + pz*sz[m];
        float d = pw + sw[m] - 2.0f * dot;    // same expansion as reference
        if (d < d2v) {
            if (d < d1) {
                if (d < d0) { d2v=d1; i2=i1; d1=d0; i1=i0; d0=d; i0=m; }
                else        { d2v=d1; i2=i1; d1=d;  i1=m; }
            } else          { d2v=d;  i2=m; }
        }
    }
    int base = (p * NCHUNK + chunk) * 3;
    pdist[base] = d0;      pdist[base+1] = d1;      pdist[base+2] = d2v;
    pidx[base]  = m0 + i0; pidx[base+1]  = m0 + i1; pidx[base+2]  = m0 + i2;
}

// ---------------------------------------------------------------------------
// K1b: merge 8 sorted top-3 partials per point (chunk-major, strict < keeps
// the reference's lowest-index-on-tie order).
// ---------------------------------------------------------------------------
__global__ __launch_bounds__(256) void knn_merge_kernel(
    const float* __restrict__ pdist, const int* __restrict__ pidx,
    int* __restrict__ knn_idx, float* __restrict__ knn_w)
{
    int p = blockIdx.x * 256 + threadIdx.x;
    float d0 = 1e30f, d1 = 1e30f, d2v = 1e30f;
    int   i0 = 0, i1 = 0, i2 = 0;
    int base = p * NCHUNK * 3;
    #pragma unroll
    for (int c = 0; c < NCHUNK * 3; ++c) {
        float d = pdist[base + c];
        int   i = pidx[base + c];
        if (d < d2v) {
            if (d < d1) {
                if (d < d0) { d2v=d1; i2=i1; d1=d0; i1=i0; d0=d; i0=i; }
                else        { d2v=d1; i2=i1; d1=d;  i1=i; }
            } else          { d2v=d;  i2=i; }
        }
    }
    float w0 = 1.0f / fmaxf(d0,  1e-16f);
    float w1 = 1.0f / fmaxf(d1,  1e-16f);
    float w2 = 1.0f / fmaxf(d2v, 1e-16f);
    float inv = 1.0f / (w0 + w1 + w2);
    knn_idx[3*p] = i0; knn_idx[3*p+1] = i1; knn_idx[3*p+2] = i2;
    knn_w[3*p] = w0*inv; knn_w[3*p+1] = w1*inv; knn_w[3*p+2] = w2*inv;
}

// ---------------------------------------------------------------------------
// K2: convert W1/W2 to bf16 (tiny)
// ---------------------------------------------------------------------------
__global__ __launch_bounds__(256) void convw_kernel(
    const float* __restrict__ W1, const float* __restrict__ W2,
    unsigned short* __restrict__ W1b, unsigned short* __restrict__ W2b)
{
    int i = blockIdx.x * 256 + threadIdx.x;
    if (i < COUT * KCH) W1b[i] = f2bf(W1[i]);
    else {
        int j = i - COUT * KCH;
        if (j < COUT * COUT) W2b[j] = f2bf(W2[j]);
    }
}

// ---------------------------------------------------------------------------
// K3: pf [b][c][n] fp32  ->  HbT[(b*NN+n)*KCH + c] bf16  (c = 0..127)
// ---------------------------------------------------------------------------
__global__ __launch_bounds__(256) void pf_t_kernel(
    const float* __restrict__ pf, unsigned short* __restrict__ HbT)
{
    __shared__ float ls[64][129];
    int blk = blockIdx.x;
    int b = blk >> 6, n0 = (blk & 63) * 64;
    int t = threadIdx.x;
    const float* src = pf + (size_t)b * CSK * NN;
    #pragma unroll
    for (int i = 0; i < 32; ++i) {
        int id = t + i * 256;
        int c = id >> 6, nn = id & 63;
        ls[nn][c] = src[(size_t)c * NN + n0 + nn];
    }
    __syncthreads();
    int row = t & 63, ch = (t >> 6) * 32;
    unsigned short* dst = HbT + ((size_t)b * NN + n0 + row) * KCH + ch;
    #pragma unroll
    for (int g = 0; g < 4; ++g) {
        ushort8v w;
        #pragma unroll
        for (int j = 0; j < 8; ++j) w[j] = f2bf(ls[row][ch + g*8 + j]);
        *(ushort8v*)&dst[g*8] = w;
    }
}

// ---------------------------------------------------------------------------
// K4: interp + scramble. H_interp(b, cv, n=hi*256+nlo) = interp(q=cv*16+hi, nlo)
// Block = (b*16+hi, ch): 32 channel-slots cv = ch*32..+31, all 256 nlo.
// Grid (256, 8) = 2048 blocks, ~17 KB LDS -> 8 blocks/CU -> 32 waves/CU.
// ---------------------------------------------------------------------------
__global__ __launch_bounds__(256) void interp_kernel(
    const float* __restrict__ cf, const int* __restrict__ knn_idx,
    const float* __restrict__ knn_w, unsigned short* __restrict__ HbT)
{
    __shared__ int   li[CVB][3];
    __shared__ float lw[CVB][3];
    __shared__ unsigned short tile[CVB][258];
    int bh = blockIdx.x;
    int b = bh >> 4, hi = bh & 15;
    int ch = blockIdx.y;
    int t = threadIdx.x;
    if (t < CVB) {
        int P = b * NN + (ch * CVB + t) * 16 + hi;
        li[t][0] = knn_idx[3*P]; li[t][1] = knn_idx[3*P+1]; li[t][2] = knn_idx[3*P+2];
        lw[t][0] = knn_w[3*P];   lw[t][1] = knn_w[3*P+1];   lw[t][2] = knn_w[3*P+2];
    }
    __syncthreads();
    const float* cfb = cf + (size_t)b * MM * CIN;
    #pragma unroll 4
    for (int cv = 0; cv < CVB; ++cv) {
        float v = lw[cv][0] * cfb[(size_t)li[cv][0] * CIN + t]
                + lw[cv][1] * cfb[(size_t)li[cv][1] * CIN + t]
                + lw[cv][2] * cfb[(size_t)li[cv][2] * CIN + t];
        tile[cv][t] = f2bf(v);
    }
    __syncthreads();
    size_t dstbase = ((size_t)b * NN + hi * 256 + t) * KCH + CSK + ch * CVB;
    #pragma unroll
    for (int g = 0; g < CVB / 8; ++g) {
        ushort8v w;
        #pragma unroll
        for (int j = 0; j < 8; ++j) w[j] = tile[g*8 + j][t];
        *(ushort8v*)&HbT[dstbase + g*8] = w;
    }
}

// ---------------------------------------------------------------------------
// K5: GEMM1 (MFMA bf16): h1T[p][o] = bf16( sum_c W1[o][c]*H[c][p] + b1[o] )
// ---------------------------------------------------------------------------
__global__ __launch_bounds__(256) void gemm1_kernel(
    const unsigned short* __restrict__ HbT, const unsigned short* __restrict__ W1b,
    const float* __restrict__ b1, unsigned short* __restrict__ h1T)
{
    __shared__ __align__(16) unsigned short As[128][40];
    __shared__ __align__(16) unsigned short Bs[128][40];
    int pp0 = blockIdx.x * 128;
    int o0  = blockIdx.y * 128;
    int t = threadIdx.x;
    int wid = t >> 6, lane = t & 63;
    int wr = wid >> 1, wc = wid & 1;
    int lr = lane & 15, lk = lane >> 4;

    f32x4 acc[4][4] = {};

    for (int c0 = 0; c0 < KCH; c0 += 32) {
        #pragma unroll
        for (int i = 0; i < 2; ++i) {
            int id = t + i * 256;
            int row = id >> 2, q = id & 3;
            *(ushort8v*)&As[row][q*8] =
                *(const ushort8v*)&W1b[(size_t)(o0 + row) * KCH + c0 + q*8];
            *(ushort8v*)&Bs[row][q*8] =
                *(const ushort8v*)&HbT[(size_t)(pp0 + row) * KCH + c0 + q*8];
        }
        __syncthreads();
        bf16x8 af[4], bfr[4];
        #pragma unroll
        for (int m = 0; m < 4; ++m) af[m] = *(const bf16x8*)&As[wr*64 + m*16 + lr][lk*8];
        #pragma unroll
        for (int n = 0; n < 4; ++n) bfr[n] = *(const bf16x8*)&Bs[wc*64 + n*16 + lr][lk*8];
        #pragma unroll
        for (int m = 0; m < 4; ++m)
            #pragma unroll
            for (int n = 0; n < 4; ++n)
                acc[m][n] = __builtin_amdgcn_mfma_f32_16x16x32_bf16(af[m], bfr[n], acc[m][n], 0, 0, 0);
        __syncthreads();
    }
    #pragma unroll
    for (int n = 0; n < 4; ++n) {
        int p = pp0 + wc*64 + n*16 + lr;
        #pragma unroll
        for (int m = 0; m < 4; ++m) {
            int o = o0 + wr*64 + m*16 + lk*4;
            f32x4 v = acc[m][n];
            ushort4v w;
            w[0] = f2bf(v[0] + b1[o]);
            w[1] = f2bf(v[1] + b1[o+1]);
            w[2] = f2bf(v[2] + b1[o+2]);
            w[3] = f2bf(v[3] + b1[o+3]);
            *(ushort4v*)&h1T[(size_t)p * COUT + o] = w;
        }
    }
}

// ---------------------------------------------------------------------------
// K6: per-channel partial sums over h1T (columnar, coalesced, deterministic)
// ---------------------------------------------------------------------------
__global__ __launch_bounds__(256) void stats_kernel(
    const unsigned short* __restrict__ h1T, float* __restrict__ psum, float* __restrict__ psq)
{
    __shared__ float ls[256][8];
    int seg = blockIdx.x, t = threadIdx.x;
    int col8 = (t & 31) * 8, rg = t >> 5;
    float s[8] = {}, q[8] = {};
    size_t base = (size_t)seg * SEGROWS * COUT;
    for (int p = rg; p < SEGROWS; p += 8) {
        ushort8v v = *(const ushort8v*)&h1T[base + (size_t)p * COUT + col8];
        #pragma unroll
        for (int j = 0; j < 8; ++j) { float f = bf2f(v[j]); s[j] += f; q[j] = fmaf(f, f, q[j]); }
    }
    #pragma unroll
    for (int j = 0; j < 8; ++j) ls[t][j] = s[j];
    __syncthreads();
    for (int off = 128; off >= 32; off >>= 1) {
        if (t < off) {
            #pragma unroll
            for (int j = 0; j < 8; ++j) ls[t][j] += ls[t + off][j];
        }
        __syncthreads();
    }
    if (t < 32) {
        #pragma unroll
        for (int j = 0; j < 8; ++j) psum[seg * COUT + t*8 + j] = ls[t][j];
    }
    __syncthreads();
    #pragma unroll
    for (int j = 0; j < 8; ++j) ls[t][j] = q[j];
    __syncthreads();
    for (int off = 128; off >= 32; off >>= 1) {
        if (t < off) {
            #pragma unroll
            for (int j = 0; j < 8; ++j) ls[t][j] += ls[t + off][j];
        }
        __syncthreads();
    }
    if (t < 32) {
        #pragma unroll
        for (int j = 0; j < 8; ++j) psq[seg * COUT + t*8 + j] = ls[t][j];
    }
}

__global__ __launch_bounds__(256) void bnfin_kernel(
    const float* __restrict__ psum, const float* __restrict__ psq,
    const float* __restrict__ gamma, const float* __restrict__ beta,
    float* __restrict__ bnscale, float* __restrict__ bnshift)
{
    int o = threadIdx.x;
    float S = 0.f, Q = 0.f;
    for (int s = 0; s < NSEG; ++s) { S += psum[s * COUT + o]; Q += psq[s * COUT + o]; }
    float mean = S * (1.0f / NP);
    float var  = Q * (1.0f / NP) - mean * mean;
    float sc = gamma[o] * rsqrtf(var + 1e-5f);
    bnscale[o] = sc;
    bnshift[o] = fmaf(-mean, sc, beta[o]);
}

// ---------------------------------------------------------------------------
// K7: GEMM2 (MFMA bf16) with BN+ReLU fused into B-staging.
// ---------------------------------------------------------------------------
__global__ __launch_bounds__(256) void gemm2_kernel(
    const unsigned short* __restrict__ h1T, const unsigned short* __restrict__ W2b,
    const float* __restrict__ b2, const float* __restrict__ bnscale,
    const float* __restrict__ bnshift, float* __restrict__ out)
{
    __shared__ __align__(16) unsigned short As[128][40];
    __shared__ __align__(16) unsigned short Bs[128][40];
    __shared__ float scs[COUT], shs[COUT];
    int pp0 = blockIdx.x * 128;
    int o0  = blockIdx.y * 128;
    int t = threadIdx.x;
    scs[t] = bnscale[t]; shs[t] = bnshift[t];
    int wid = t >> 6, lane = t & 63;
    int wr = wid >> 1, wc = wid & 1;
    int lr = lane & 15, lk = lane >> 4;
    f32x4 acc[4][4] = {};
    __syncthreads();

    for (int c0 = 0; c0 < COUT; c0 += 32) {
        #pragma unroll
        for (int i = 0; i < 2; ++i) {
            int id = t + i * 256;
            int row = id >> 2, q = id & 3;
            *(ushort8v*)&As[row][q*8] =
                *(const ushort8v*)&W2b[(size_t)(o0 + row) * COUT + c0 + q*8];
            ushort8v hv = *(const ushort8v*)&h1T[(size_t)(pp0 + row) * COUT + c0 + q*8];
            ushort8v bv;
            #pragma unroll
            for (int j = 0; j < 8; ++j) {
                float f = fmaf(bf2f(hv[j]), scs[c0 + q*8 + j], shs[c0 + q*8 + j]);
                bv[j] = f2bf(fmaxf(f, 0.0f));
            }
            *(ushort8v*)&Bs[row][q*8] = bv;
        }
        __syncthreads();
        bf16x8 af[4], bfr[4];
        #pragma unroll
        for (int m = 0; m < 4; ++m) af[m] = *(const bf16x8*)&As[wr*64 + m*16 + lr][lk*8];
        #pragma unroll
        for (int n = 0; n < 4; ++n) bfr[n] = *(const bf16x8*)&Bs[wc*64 + n*16 + lr][lk*8];
        #pragma unroll
        for (int m = 0; m < 4; ++m)
            #pragma unroll
            for (int n = 0; n < 4; ++n)
                acc[m][n] = __builtin_amdgcn_mfma_f32_16x16x32_bf16(af[m], bfr[n], acc[m][n], 0, 0, 0);
        __syncthreads();
    }
    #pragma unroll
    for (int n = 0; n < 4; ++n) {
        int p = pp0 + wc*64 + n*16 + lr;
        int b = p >> 12, nn = p & (NN - 1);
        #pragma unroll
        for (int m = 0; m < 4; ++m) {
            int o = o0 + wr*64 + m*16 + lk*4;
            f32x4 v = acc[m][n];
            float* dst = out + ((size_t)(b * COUT + o)) * NN + nn;
            dst[0]        = v[0] + b2[o];
            dst[NN]       = v[1] + b2[o+1];
            dst[2*NN]     = v[2] + b2[o+2];
            dst[3*NN]     = v[3] + b2[o+3];
        }
    }
}

// ---------------------------------------------------------------------------
extern "C" void kernel_launch(void* const* d_in, const int* in_sizes, int n_in,
                              void* d_out, int out_size, void* d_ws, size_t ws_size,
                              hipStream_t stream)
{
    const float* pts   = (const float*)d_in[0];
    const float* pf    = (const float*)d_in[1];
    const float* cen   = (const float*)d_in[2];
    const float* cf    = (const float*)d_in[3];
    const float* W1    = (const float*)d_in[4];
    const float* b1    = (const float*)d_in[5];
    const float* gamma = (const float*)d_in[6];
    const float* beta  = (const float*)d_in[7];
    const float* W2    = (const float*)d_in[8];
    const float* b2    = (const float*)d_in[9];
    float* out = (float*)d_out;

    char* ws = (char*)d_ws;
    size_t off = 0;
    unsigned short* HbT = (unsigned short*)(ws + off); off += (size_t)NP * KCH * 2;
    unsigned short* h1T = (unsigned short*)(ws + off); off += (size_t)NP * COUT * 2;
    unsigned short* W1b = (unsigned short*)(ws + off); off += (size_t)COUT * KCH * 2;
    unsigned short* W2b = (unsigned short*)(ws + off); off += (size_t)COUT * COUT * 2;
    int*   knn_idx = (int*)(ws + off);   off += (size_t)NP * 3 * sizeof(int);
    float* knn_w   = (float*)(ws + off); off += (size_t)NP * 3 * sizeof(float);
    float* pdist   = (float*)(ws + off); off += (size_t)NP * NCHUNK * 3 * sizeof(float);
    int*   pidx    = (int*)(ws + off);   off += (size_t)NP * NCHUNK * 3 * sizeof(int);
    float* psum    = (float*)(ws + off); off += (size_t)NSEG * COUT * sizeof(float);
    float* psq     = (float*)(ws + off); off += (size_t)NSEG * COUT * sizeof(float);
    float* bnscale = (float*)(ws + off); off += 1024;
    float* bnshift = (float*)(ws + off); off += 1024;
    (void)ws_size; (void)in_sizes; (void)n_in; (void)out_size;

    hipLaunchKernelGGL(convw_kernel,    dim3(640),               dim3(256), 0, stream,
                       W1, W2, W1b, W2b);
    hipLaunchKernelGGL(knn_part_kernel, dim3(NP / 256, NCHUNK),  dim3(256), 0, stream,
                       pts, cen, pdist, pidx);
    hipLaunchKernelGGL(knn_merge_kernel, dim3(NP / 256),         dim3(256), 0, stream,
                       pdist, pidx, knn_idx, knn_w);
    hipLaunchKernelGGL(pf_t_kernel,     dim3(BB * 64),           dim3(256), 0, stream,
                       pf, HbT);
    hipLaunchKernelGGL(interp_kernel,   dim3(256, 8),            dim3(256), 0, stream,
                       cf, knn_idx, knn_w, HbT);
    hipLaunchKernelGGL(gemm1_kernel,    dim3(NP / 128, 2),       dim3(256), 0, stream,
                       HbT, W1b, b1, h1T);
    hipLaunchKernelGGL(stats_kernel,    dim3(NSEG),              dim3(256), 0, stream,
                       h1T, psum, psq);
    hipLaunchKernelGGL(bnfin_kernel,    dim3(1),                 dim3(256), 0, stream,
                       psum, psq, gamma, beta, bnscale, bnshift);
    hipLaunchKernelGGL(gemm2_kernel,    dim3(NP / 128, 2),       dim3(256), 0, stream,
                       h1T, W2b, b2, bnscale, bnshift, out);
}

// Round 6
// 181.346 us; speedup vs baseline: 2.8977x; 1.0286x over previous
//
#include <hip/hip_runtime.h>

#define BB   16
#define NN   4096
#define MM   1024
#define CIN  256
#define CSK  128
#define COUT 256
#define KCH  384              // CIN + CSK
#define NP   65536            // BB * NN
#define NSEG 256
#define SEGROWS 256           // NP / NSEG
#define NCHUNK 8
#define MCH  (MM / NCHUNK)    // 128
#define CVB  32               // interp channel-slots per block

typedef __attribute__((ext_vector_type(8))) short bf16x8;
typedef __attribute__((ext_vector_type(4))) float f32x4;
typedef __attribute__((ext_vector_type(8))) unsigned short ushort8v;
typedef __attribute__((ext_vector_type(4))) unsigned short ushort4v;

static __device__ __forceinline__ unsigned short f2bf(float f) {
    unsigned u = __builtin_bit_cast(unsigned, f);
    u += 0x7fffu + ((u >> 16) & 1u);          // round-to-nearest-even
    return (unsigned short)(u >> 16);
}
static __device__ __forceinline__ float bf2f(unsigned short h) {
    unsigned u = ((unsigned)h) << 16;
    return __builtin_bit_cast(float, u);
}

// ---------------------------------------------------------------------------
// K1a: partial KNN — 256 points x 128 centroids per block.
// Full-precision fp32 distance compare (same expression as the passing
// rounds); branchless 3-mask sorted-insert: 3 v_cmp + 10 v_cndmask per
// candidate instead of the ~15-cndmask nested cascade.
// ---------------------------------------------------------------------------
__global__ __launch_bounds__(256) void knn_part_kernel(
    const float* __restrict__ pts, const float* __restrict__ cen,
    float* __restrict__ pdist, int* __restrict__ pidx)
{
    __shared__ float4 sc[MCH];

    int p0    = blockIdx.x * 256;
    int chunk = blockIdx.y;
    int b     = p0 >> 12;
    int m0    = chunk * MCH;
    const float* cb = cen + (size_t)b * 3 * MM + 3 * m0;
    if (threadIdx.x < MCH) {
        int m = threadIdx.x;
        float x = cb[3*m], y = cb[3*m+1], z = cb[3*m+2];
        sc[m] = make_float4(x, y, z, x*x + y*y + z*z);
    }
    __syncthreads();

    int p = p0 + threadIdx.x;
    int n = p & (NN - 1);
    const float* pb = pts + (size_t)b * 3 * NN;
    float px = pb[3*n], py = pb[3*n+1], pz = pb[3*n+2];
    float pw = px*px + py*py + pz*pz;

    float d0 = 1e30f, d1 = 1e30f, d2v = 1e30f;
    int   i0 = 0, i1 = 0, i2 = 0;
    #pragma unroll 8
    for (int m = 0; m < MCH; ++m) {
        float4 c = sc[m];
        float dot = px*c.x + py*c.y + pz*c.z;
        float d = pw + c.w - 2.0f * dot;      // same expansion as reference
        bool c2 = d < d2v, c1 = d < d1, c0 = d < d0;
        // sorted insert, update back-to-front so reads see old values
        d2v = c1 ? d1 : (c2 ? d : d2v);
        i2  = c1 ? i1 : (c2 ? m : i2);
        d1  = c0 ? d0 : (c1 ? d : d1);
        i1  = c0 ? i0 : (c1 ? m : i1);
        d0  = c0 ? d  : d0;
        i0  = c0 ? m  : i0;
    }
    int base = (p * NCHUNK + chunk) * 3;
    pdist[base] = d0;      pdist[base+1] = d1;      pdist[base+2] = d2v;
    pidx[base]  = m0 + i0; pidx[base+1]  = m0 + i1; pidx[base+2]  = m0 + i2;
}

// ---------------------------------------------------------------------------
// K1b: merge 8 sorted top-3 partials per point (chunk-major, strict < keeps
// the reference's lowest-index-on-tie order).
// ---------------------------------------------------------------------------
__global__ __launch_bounds__(256) void knn_merge_kernel(
    const float* __restrict__ pdist, const int* __restrict__ pidx,
    int* __restrict__ knn_idx, float* __restrict__ knn_w)
{
    int p = blockIdx.x * 256 + threadIdx.x;
    float d0 = 1e30f, d1 = 1e30f, d2v = 1e30f;
    int   i0 = 0, i1 = 0, i2 = 0;
    int base = p * NCHUNK * 3;
    #pragma unroll
    for (int c = 0; c < NCHUNK * 3; ++c) {
        float d = pdist[base + c];
        int   i = pidx[base + c];
        bool c2 = d < d2v, c1 = d < d1, c0 = d < d0;
        d2v = c1 ? d1 : (c2 ? d : d2v);
        i2  = c1 ? i1 : (c2 ? i : i2);
        d1  = c0 ? d0 : (c1 ? d : d1);
        i1  = c0 ? i0 : (c1 ? i : i1);
        d0  = c0 ? d  : d0;
        i0  = c0 ? i  : i0;
    }
    float w0 = 1.0f / fmaxf(d0,  1e-16f);
    float w1 = 1.0f / fmaxf(d1,  1e-16f);
    float w2 = 1.0f / fmaxf(d2v, 1e-16f);
    float inv = 1.0f / (w0 + w1 + w2);
    knn_idx[3*p] = i0; knn_idx[3*p+1] = i1; knn_idx[3*p+2] = i2;
    knn_w[3*p] = w0*inv; knn_w[3*p+1] = w1*inv; knn_w[3*p+2] = w2*inv;
}

// ---------------------------------------------------------------------------
// K2: convert W1/W2 to bf16 (tiny)
// ---------------------------------------------------------------------------
__global__ __launch_bounds__(256) void convw_kernel(
    const float* __restrict__ W1, const float* __restrict__ W2,
    unsigned short* __restrict__ W1b, unsigned short* __restrict__ W2b)
{
    int i = blockIdx.x * 256 + threadIdx.x;
    if (i < COUT * KCH) W1b[i] = f2bf(W1[i]);
    else {
        int j = i - COUT * KCH;
        if (j < COUT * COUT) W2b[j] = f2bf(W2[j]);
    }
}

// ---------------------------------------------------------------------------
// K3: pf [b][c][n] fp32  ->  HbT[(b*NN+n)*KCH + c] bf16  (c = 0..127)
// ---------------------------------------------------------------------------
__global__ __launch_bounds__(256) void pf_t_kernel(
    const float* __restrict__ pf, unsigned short* __restrict__ HbT)
{
    __shared__ float ls[64][129];
    int blk = blockIdx.x;
    int b = blk >> 6, n0 = (blk & 63) * 64;
    int t = threadIdx.x;
    const float* src = pf + (size_t)b * CSK * NN;
    #pragma unroll
    for (int i = 0; i < 32; ++i) {
        int id = t + i * 256;
        int c = id >> 6, nn = id & 63;
        ls[nn][c] = src[(size_t)c * NN + n0 + nn];
    }
    __syncthreads();
    int row = t & 63, ch = (t >> 6) * 32;
    unsigned short* dst = HbT + ((size_t)b * NN + n0 + row) * KCH + ch;
    #pragma unroll
    for (int g = 0; g < 4; ++g) {
        ushort8v w;
        #pragma unroll
        for (int j = 0; j < 8; ++j) w[j] = f2bf(ls[row][ch + g*8 + j]);
        *(ushort8v*)&dst[g*8] = w;
    }
}

// ---------------------------------------------------------------------------
// K4: interp + scramble. H_interp(b, cv, n=hi*256+nlo) = interp(q=cv*16+hi, nlo)
// Grid (256, 8) = 2048 blocks.
// ---------------------------------------------------------------------------
__global__ __launch_bounds__(256) void interp_kernel(
    const float* __restrict__ cf, const int* __restrict__ knn_idx,
    const float* __restrict__ knn_w, unsigned short* __restrict__ HbT)
{
    __shared__ int   li[CVB][3];
    __shared__ float lw[CVB][3];
    __shared__ unsigned short tile[CVB][258];
    int bh = blockIdx.x;
    int b = bh >> 4, hi = bh & 15;
    int ch = blockIdx.y;
    int t = threadIdx.x;
    if (t < CVB) {
        int P = b * NN + (ch * CVB + t) * 16 + hi;
        li[t][0] = knn_idx[3*P]; li[t][1] = knn_idx[3*P+1]; li[t][2] = knn_idx[3*P+2];
        lw[t][0] = knn_w[3*P];   lw[t][1] = knn_w[3*P+1];   lw[t][2] = knn_w[3*P+2];
    }
    __syncthreads();
    const float* cfb = cf + (size_t)b * MM * CIN;
    #pragma unroll 4
    for (int cv = 0; cv < CVB; ++cv) {
        float v = lw[cv][0] * cfb[(size_t)li[cv][0] * CIN + t]
                + lw[cv][1] * cfb[(size_t)li[cv][1] * CIN + t]
                + lw[cv][2] * cfb[(size_t)li[cv][2] * CIN + t];
        tile[cv][t] = f2bf(v);
    }
    __syncthreads();
    size_t dstbase = ((size_t)b * NN + hi * 256 + t) * KCH + CSK + ch * CVB;
    #pragma unroll
    for (int g = 0; g < CVB / 8; ++g) {
        ushort8v w;
        #pragma unroll
        for (int j = 0; j < 8; ++j) w[j] = tile[g*8 + j][t];
        *(ushort8v*)&HbT[dstbase + g*8] = w;
    }
}

// ---------------------------------------------------------------------------
// K5: GEMM1 (MFMA bf16) with register prefetch of the next K-tile.
// h1T[p][o] = bf16( sum_c W1[o][c]*H[c][p] + b1[o] )
// ---------------------------------------------------------------------------
__global__ __launch_bounds__(256) void gemm1_kernel(
    const unsigned short* __restrict__ HbT, const unsigned short* __restrict__ W1b,
    const float* __restrict__ b1, unsigned short* __restrict__ h1T)
{
    __shared__ __align__(16) unsigned short As[128][40];
    __shared__ __align__(16) unsigned short Bs[128][40];
    int pp0 = blockIdx.x * 128;
    int o0  = blockIdx.y * 128;
    int t = threadIdx.x;
    int wid = t >> 6, lane = t & 63;
    int wr = wid >> 1, wc = wid & 1;
    int lr = lane & 15, lk = lane >> 4;

    int rowi[2], qi[2];
    ushort8v ra[2], rb[2];
    #pragma unroll
    for (int i = 0; i < 2; ++i) { int id = t + i*256; rowi[i] = id >> 2; qi[i] = id & 3; }
    #pragma unroll
    for (int i = 0; i < 2; ++i) {
        ra[i] = *(const ushort8v*)&W1b[(size_t)(o0 + rowi[i]) * KCH + qi[i]*8];
        rb[i] = *(const ushort8v*)&HbT[(size_t)(pp0 + rowi[i]) * KCH + qi[i]*8];
    }

    f32x4 acc[4][4] = {};

    for (int c0 = 0; c0 < KCH; c0 += 32) {
        #pragma unroll
        for (int i = 0; i < 2; ++i) {
            *(ushort8v*)&As[rowi[i]][qi[i]*8] = ra[i];
            *(ushort8v*)&Bs[rowi[i]][qi[i]*8] = rb[i];
        }
        __syncthreads();
        int cn = (c0 + 32 < KCH) ? c0 + 32 : c0;   // last iter: redundant reload
        #pragma unroll
        for (int i = 0; i < 2; ++i) {
            ra[i] = *(const ushort8v*)&W1b[(size_t)(o0 + rowi[i]) * KCH + cn + qi[i]*8];
            rb[i] = *(const ushort8v*)&HbT[(size_t)(pp0 + rowi[i]) * KCH + cn + qi[i]*8];
        }
        bf16x8 af[4], bfr[4];
        #pragma unroll
        for (int m = 0; m < 4; ++m) af[m] = *(const bf16x8*)&As[wr*64 + m*16 + lr][lk*8];
        #pragma unroll
        for (int n = 0; n < 4; ++n) bfr[n] = *(const bf16x8*)&Bs[wc*64 + n*16 + lr][lk*8];
        #pragma unroll
        for (int m = 0; m < 4; ++m)
            #pragma unroll
            for (int n = 0; n < 4; ++n)
                acc[m][n] = __builtin_amdgcn_mfma_f32_16x16x32_bf16(af[m], bfr[n], acc[m][n], 0, 0, 0);
        __syncthreads();
    }
    #pragma unroll
    for (int n = 0; n < 4; ++n) {
        int p = pp0 + wc*64 + n*16 + lr;
        #pragma unroll
        for (int m = 0; m < 4; ++m) {
            int o = o0 + wr*64 + m*16 + lk*4;
            f32x4 v = acc[m][n];
            ushort4v w;
            w[0] = f2bf(v[0] + b1[o]);
            w[1] = f2bf(v[1] + b1[o+1]);
            w[2] = f2bf(v[2] + b1[o+2]);
            w[3] = f2bf(v[3] + b1[o+3]);
            *(ushort4v*)&h1T[(size_t)p * COUT + o] = w;
        }
    }
}

// ---------------------------------------------------------------------------
// K6: per-channel partial sums over h1T (columnar, coalesced, deterministic)
// ---------------------------------------------------------------------------
__global__ __launch_bounds__(256) void stats_kernel(
    const unsigned short* __restrict__ h1T, float* __restrict__ psum, float* __restrict__ psq)
{
    __shared__ float ls[256][8];
    int seg = blockIdx.x, t = threadIdx.x;
    int col8 = (t & 31) * 8, rg = t >> 5;
    float s[8] = {}, q[8] = {};
    size_t base = (size_t)seg * SEGROWS * COUT;
    for (int p = rg; p < SEGROWS; p += 8) {
        ushort8v v = *(const ushort8v*)&h1T[base + (size_t)p * COUT + col8];
        #pragma unroll
        for (int j = 0; j < 8; ++j) { float f = bf2f(v[j]); s[j] += f; q[j] = fmaf(f, f, q[j]); }
    }
    #pragma unroll
    for (int j = 0; j < 8; ++j) ls[t][j] = s[j];
    __syncthreads();
    for (int off = 128; off >= 32; off >>= 1) {
        if (t < off) {
            #pragma unroll
            for (int j = 0; j < 8; ++j) ls[t][j] += ls[t + off][j];
        }
        __syncthreads();
    }
    if (t < 32) {
        #pragma unroll
        for (int j = 0; j < 8; ++j) psum[seg * COUT + t*8 + j] = ls[t][j];
    }
    __syncthreads();
    #pragma unroll
    for (int j = 0; j < 8; ++j) ls[t][j] = q[j];
    __syncthreads();
    for (int off = 128; off >= 32; off >>= 1) {
        if (t < off) {
            #pragma unroll
            for (int j = 0; j < 8; ++j) ls[t][j] += ls[t + off][j];
        }
        __syncthreads();
    }
    if (t < 32) {
        #pragma unroll
        for (int j = 0; j < 8; ++j) psq[seg * COUT + t*8 + j] = ls[t][j];
    }
}

__global__ __launch_bounds__(256) void bnfin_kernel(
    const float* __restrict__ psum, const float* __restrict__ psq,
    const float* __restrict__ gamma, const float* __restrict__ beta,
    float* __restrict__ bnscale, float* __restrict__ bnshift)
{
    int o = threadIdx.x;
    float S = 0.f, Q = 0.f;
    for (int s = 0; s < NSEG; ++s) { S += psum[s * COUT + o]; Q += psq[s * COUT + o]; }
    float mean = S * (1.0f / NP);
    float var  = Q * (1.0f / NP) - mean * mean;
    float sc = gamma[o] * rsqrtf(var + 1e-5f);
    bnscale[o] = sc;
    bnshift[o] = fmaf(-mean, sc, beta[o]);
}

// ---------------------------------------------------------------------------
// K7: GEMM2 (MFMA bf16), BN+ReLU fused at LDS-write, register prefetch.
// ---------------------------------------------------------------------------
__global__ __launch_bounds__(256) void gemm2_kernel(
    const unsigned short* __restrict__ h1T, const unsigned short* __restrict__ W2b,
    const float* __restrict__ b2, const float* __restrict__ bnscale,
    const float* __restrict__ bnshift, float* __restrict__ out)
{
    __shared__ __align__(16) unsigned short As[128][40];
    __shared__ __align__(16) unsigned short Bs[128][40];
    __shared__ float scs[COUT], shs[COUT];
    int pp0 = blockIdx.x * 128;
    int o0  = blockIdx.y * 128;
    int t = threadIdx.x;
    scs[t] = bnscale[t]; shs[t] = bnshift[t];
    int wid = t >> 6, lane = t & 63;
    int wr = wid >> 1, wc = wid & 1;
    int lr = lane & 15, lk = lane >> 4;

    int rowi[2], qi[2];
    ushort8v ra[2], rb[2];
    #pragma unroll
    for (int i = 0; i < 2; ++i) { int id = t + i*256; rowi[i] = id >> 2; qi[i] = id & 3; }
    #pragma unroll
    for (int i = 0; i < 2; ++i) {
        ra[i] = *(const ushort8v*)&W2b[(size_t)(o0 + rowi[i]) * COUT + qi[i]*8];
        rb[i] = *(const ushort8v*)&h1T[(size_t)(pp0 + rowi[i]) * COUT + qi[i]*8];
    }
    f32x4 acc[4][4] = {};
    __syncthreads();

    for (int c0 = 0; c0 < COUT; c0 += 32) {
        #pragma unroll
        for (int i = 0; i < 2; ++i) {
            *(ushort8v*)&As[rowi[i]][qi[i]*8] = ra[i];
            ushort8v bv;
            #pragma unroll
            for (int j = 0; j < 8; ++j) {
                float f = fmaf(bf2f(rb[i][j]), scs[c0 + qi[i]*8 + j], shs[c0 + qi[i]*8 + j]);
                bv[j] = f2bf(fmaxf(f, 0.0f));
            }
            *(ushort8v*)&Bs[rowi[i]][qi[i]*8] = bv;
        }
        __syncthreads();
        int cn = (c0 + 32 < COUT) ? c0 + 32 : c0;
        #pragma unroll
        for (int i = 0; i < 2; ++i) {
            ra[i] = *(const ushort8v*)&W2b[(size_t)(o0 + rowi[i]) * COUT + cn + qi[i]*8];
            rb[i] = *(const ushort8v*)&h1T[(size_t)(pp0 + rowi[i]) * COUT + cn + qi[i]*8];
        }
        bf16x8 af[4], bfr[4];
        #pragma unroll
        for (int m = 0; m < 4; ++m) af[m] = *(const bf16x8*)&As[wr*64 + m*16 + lr][lk*8];
        #pragma unroll
        for (int n = 0; n < 4; ++n) bfr[n] = *(const bf16x8*)&Bs[wc*64 + n*16 + lr][lk*8];
        #pragma unroll
        for (int m = 0; m < 4; ++m)
            #pragma unroll
            for (int n = 0; n < 4; ++n)
                acc[m][n] = __builtin_amdgcn_mfma_f32_16x16x32_bf16(af[m], bfr[n], acc[m][n], 0, 0, 0);
        __syncthreads();
    }
    #pragma unroll
    for (int n = 0; n < 4; ++n) {
        int p = pp0 + wc*64 + n*16 + lr;
        int b = p >> 12, nn = p & (NN - 1);
        #pragma unroll
        for (int m = 0; m < 4; ++m) {
            int o = o0 + wr*64 + m*16 + lk*4;
            f32x4 v = acc[m][n];
            float* dst = out + ((size_t)(b * COUT + o)) * NN + nn;
            dst[0]        = v[0] + b2[o];
            dst[NN]       = v[1] + b2[o+1];
            dst[2*NN]     = v[2] + b2[o+2];
            dst[3*NN]     = v[3] + b2[o+3];
        }
    }
}

// ---------------------------------------------------------------------------
extern "C" void kernel_launch(void* const* d_in, const int* in_sizes, int n_in,
                              void* d_out, int out_size, void* d_ws, size_t ws_size,
                              hipStream_t stream)
{
    const float* pts   = (const float*)d_in[0];
    const float* pf    = (const float*)d_in[1];
    const float* cen   = (const float*)d_in[2];
    const float* cf    = (const float*)d_in[3];
    const float* W1    = (const float*)d_in[4];
    const float* b1    = (const float*)d_in[5];
    const float* gamma = (const float*)d_in[6];
    const float* beta  = (const float*)d_in[7];
    const float* W2    = (const float*)d_in[8];
    const float* b2    = (const float*)d_in[9];
    float* out = (float*)d_out;

    char* ws = (char*)d_ws;
    size_t off = 0;
    unsigned short* HbT = (unsigned short*)(ws + off); off += (size_t)NP * KCH * 2;
    unsigned short* h1T = (unsigned short*)(ws + off); off += (size_t)NP * COUT * 2;
    unsigned short* W1b = (unsigned short*)(ws + off); off += (size_t)COUT * KCH * 2;
    unsigned short* W2b = (unsigned short*)(ws + off); off += (size_t)COUT * COUT * 2;
    int*   knn_idx = (int*)(ws + off);   off += (size_t)NP * 3 * sizeof(int);
    float* knn_w   = (float*)(ws + off); off += (size_t)NP * 3 * sizeof(float);
    float* pdist   = (float*)(ws + off); off += (size_t)NP * NCHUNK * 3 * sizeof(float);
    int*   pidx    = (int*)(ws + off);   off += (size_t)NP * NCHUNK * 3 * sizeof(int);
    float* psum    = (float*)(ws + off); off += (size_t)NSEG * COUT * sizeof(float);
    float* psq     = (float*)(ws + off); off += (size_t)NSEG * COUT * sizeof(float);
    float* bnscale = (float*)(ws + off); off += 1024;
    float* bnshift = (float*)(ws + off); off += 1024;
    (void)ws_size; (void)in_sizes; (void)n_in; (void)out_size;

    hipLaunchKernelGGL(convw_kernel,    dim3(640),               dim3(256), 0, stream,
                       W1, W2, W1b, W2b);
    hipLaunchKernelGGL(knn_part_kernel, dim3(NP / 256, NCHUNK),  dim3(256), 0, stream,
                       pts, cen, pdist, pidx);
    hipLaunchKernelGGL(knn_merge_kernel, dim3(NP / 256),         dim3(256), 0, stream,
                       pdist, pidx, knn_idx, knn_w);
    hipLaunchKernelGGL(pf_t_kernel,     dim3(BB * 64),           dim3(256), 0, stream,
                       pf, HbT);
    hipLaunchKernelGGL(interp_kernel,   dim3(256, 8),            dim3(256), 0, stream,
                       cf, knn_idx, knn_w, HbT);
    hipLaunchKernelGGL(gemm1_kernel,    dim3(NP / 128, 2),       dim3(256), 0, stream,
                       HbT, W1b, b1, h1T);
    hipLaunchKernelGGL(stats_kernel,    dim3(NSEG),              dim3(256), 0, stream,
                       h1T, psum, psq);
    hipLaunchKernelGGL(bnfin_kernel,    dim3(1),                 dim3(256), 0, stream,
                       psum, psq, gamma, beta, bnscale, bnshift);
    hipLaunchKernelGGL(gemm2_kernel,    dim3(NP / 128, 2),       dim3(256), 0, stream,
                       h1T, W2b, b2, bnscale, bnshift, out);
}

// Round 7
// 171.838 us; speedup vs baseline: 3.0580x; 1.0553x over previous
//
#include <hip/hip_runtime.h>

#define BB   16
#define NN   4096
#define MM   1024
#define CIN  256
#define CSK  128
#define COUT 256
#define KCH  384              // CIN + CSK
#define NP   65536            // BB * NN
#define NSEG 256
#define SEGROWS 256           // NP / NSEG
#define NCHUNK 8
#define MCH  (MM / NCHUNK)    // 128
#define CVB  32               // interp channel-slots per block

typedef __attribute__((ext_vector_type(8))) short bf16x8;
typedef __attribute__((ext_vector_type(4))) float f32x4;
typedef __attribute__((ext_vector_type(8))) unsigned short ushort8v;
typedef __attribute__((ext_vector_type(4))) unsigned short ushort4v;

static __device__ __forceinline__ unsigned short f2bf(float f) {
    unsigned u = __builtin_bit_cast(unsigned, f);
    u += 0x7fffu + ((u >> 16) & 1u);          // round-to-nearest-even
    return (unsigned short)(u >> 16);
}
static __device__ __forceinline__ float bf2f(unsigned short h) {
    unsigned u = ((unsigned)h) << 16;
    return __builtin_bit_cast(float, u);
}

// ---------------------------------------------------------------------------
// K0: prep = pf_t (blocks 0..1023) + convw (blocks 1024..1663)
// pf_t: pf [b][c][n] fp32 -> HbT[(b*NN+n)*KCH + c] bf16  (c = 0..127)
// convw: W1/W2 fp32 -> bf16
// ---------------------------------------------------------------------------
__global__ __launch_bounds__(256) void prep_kernel(
    const float* __restrict__ pf, unsigned short* __restrict__ HbT,
    const float* __restrict__ W1, const float* __restrict__ W2,
    unsigned short* __restrict__ W1b, unsigned short* __restrict__ W2b)
{
    __shared__ float ls[64][129];
    int blk = blockIdx.x;
    int t = threadIdx.x;
    if (blk >= 1024) {
        int i = (blk - 1024) * 256 + t;
        if (i < COUT * KCH) W1b[i] = f2bf(W1[i]);
        else {
            int j = i - COUT * KCH;
            if (j < COUT * COUT) W2b[j] = f2bf(W2[j]);
        }
        return;
    }
    int b = blk >> 6, n0 = (blk & 63) * 64;
    const float* src = pf + (size_t)b * CSK * NN;
    #pragma unroll
    for (int i = 0; i < 32; ++i) {
        int id = t + i * 256;
        int c = id >> 6, nn = id & 63;
        ls[nn][c] = src[(size_t)c * NN + n0 + nn];
    }
    __syncthreads();
    int row = t & 63, ch = (t >> 6) * 32;
    unsigned short* dst = HbT + ((size_t)b * NN + n0 + row) * KCH + ch;
    #pragma unroll
    for (int g = 0; g < 4; ++g) {
        ushort8v w;
        #pragma unroll
        for (int j = 0; j < 8; ++j) w[j] = f2bf(ls[row][ch + g*8 + j]);
        *(ushort8v*)&dst[g*8] = w;
    }
}

// ---------------------------------------------------------------------------
// K1: partial KNN — 256 points x 128 centroids per block (unchanged R6).
// ---------------------------------------------------------------------------
__global__ __launch_bounds__(256) void knn_part_kernel(
    const float* __restrict__ pts, const float* __restrict__ cen,
    float* __restrict__ pdist, int* __restrict__ pidx)
{
    __shared__ float4 sc[MCH];

    int p0    = blockIdx.x * 256;
    int chunk = blockIdx.y;
    int b     = p0 >> 12;
    int m0    = chunk * MCH;
    const float* cb = cen + (size_t)b * 3 * MM + 3 * m0;
    if (threadIdx.x < MCH) {
        int m = threadIdx.x;
        float x = cb[3*m], y = cb[3*m+1], z = cb[3*m+2];
        sc[m] = make_float4(x, y, z, x*x + y*y + z*z);
    }
    __syncthreads();

    int p = p0 + threadIdx.x;
    int n = p & (NN - 1);
    const float* pb = pts + (size_t)b * 3 * NN;
    float px = pb[3*n], py = pb[3*n+1], pz = pb[3*n+2];
    float pw = px*px + py*py + pz*pz;

    float d0 = 1e30f, d1 = 1e30f, d2v = 1e30f;
    int   i0 = 0, i1 = 0, i2 = 0;
    #pragma unroll 8
    for (int m = 0; m < MCH; ++m) {
        float4 c = sc[m];
        float dot = px*c.x + py*c.y + pz*c.z;
        float d = pw + c.w - 2.0f * dot;      // same expansion as reference
        bool c2 = d < d2v, c1 = d < d1, c0 = d < d0;
        d2v = c1 ? d1 : (c2 ? d : d2v);
        i2  = c1 ? i1 : (c2 ? m : i2);
        d1  = c0 ? d0 : (c1 ? d : d1);
        i1  = c0 ? i0 : (c1 ? m : i1);
        d0  = c0 ? d  : d0;
        i0  = c0 ? m  : i0;
    }
    int base = (p * NCHUNK + chunk) * 3;
    pdist[base] = d0;      pdist[base+1] = d1;      pdist[base+2] = d2v;
    pidx[base]  = m0 + i0; pidx[base+1]  = m0 + i1; pidx[base+2]  = m0 + i2;
}

// ---------------------------------------------------------------------------
// K2: interp + inline KNN-merge + scramble.
// Threads 0..31 merge the 8x3 sorted partials for this block's 32 points
// (chunk-major strict < keeps the reference's lowest-index-on-tie order),
// then all 256 threads gather/interp and write HbT.
// ---------------------------------------------------------------------------
__global__ __launch_bounds__(256) void interp_kernel(
    const float* __restrict__ cf, const float* __restrict__ pdist,
    const int* __restrict__ pidx, unsigned short* __restrict__ HbT)
{
    __shared__ int   li[CVB][3];
    __shared__ float lw[CVB][3];
    __shared__ unsigned short tile[CVB][258];
    int bh = blockIdx.x;
    int b = bh >> 4, hi = bh & 15;
    int ch = blockIdx.y;
    int t = threadIdx.x;
    if (t < CVB) {
        int P = b * NN + (ch * CVB + t) * 16 + hi;
        float d0 = 1e30f, d1 = 1e30f, d2v = 1e30f;
        int   i0 = 0, i1 = 0, i2 = 0;
        int base = P * NCHUNK * 3;
        #pragma unroll
        for (int c = 0; c < NCHUNK * 3; ++c) {
            float d = pdist[base + c];
            int   i = pidx[base + c];
            bool c2 = d < d2v, c1 = d < d1, c0 = d < d0;
            d2v = c1 ? d1 : (c2 ? d : d2v);
            i2  = c1 ? i1 : (c2 ? i : i2);
            d1  = c0 ? d0 : (c1 ? d : d1);
            i1  = c0 ? i0 : (c1 ? i : i1);
            d0  = c0 ? d  : d0;
            i0  = c0 ? i  : i0;
        }
        float w0 = 1.0f / fmaxf(d0,  1e-16f);
        float w1 = 1.0f / fmaxf(d1,  1e-16f);
        float w2 = 1.0f / fmaxf(d2v, 1e-16f);
        float inv = 1.0f / (w0 + w1 + w2);
        li[t][0] = i0;     li[t][1] = i1;     li[t][2] = i2;
        lw[t][0] = w0*inv; lw[t][1] = w1*inv; lw[t][2] = w2*inv;
    }
    __syncthreads();
    const float* cfb = cf + (size_t)b * MM * CIN;
    #pragma unroll 4
    for (int cv = 0; cv < CVB; ++cv) {
        float v = lw[cv][0] * cfb[(size_t)li[cv][0] * CIN + t]
                + lw[cv][1] * cfb[(size_t)li[cv][1] * CIN + t]
                + lw[cv][2] * cfb[(size_t)li[cv][2] * CIN + t];
        tile[cv][t] = f2bf(v);
    }
    __syncthreads();
    size_t dstbase = ((size_t)b * NN + hi * 256 + t) * KCH + CSK + ch * CVB;
    #pragma unroll
    for (int g = 0; g < CVB / 8; ++g) {
        ushort8v w;
        #pragma unroll
        for (int j = 0; j < 8; ++j) w[j] = tile[g*8 + j][t];
        *(ushort8v*)&HbT[dstbase + g*8] = w;
    }
}

// ---------------------------------------------------------------------------
// K3: GEMM1 (MFMA bf16) with register prefetch (unchanged R6).
// ---------------------------------------------------------------------------
__global__ __launch_bounds__(256) void gemm1_kernel(
    const unsigned short* __restrict__ HbT, const unsigned short* __restrict__ W1b,
    const float* __restrict__ b1, unsigned short* __restrict__ h1T)
{
    __shared__ __align__(16) unsigned short As[128][40];
    __shared__ __align__(16) unsigned short Bs[128][40];
    int pp0 = blockIdx.x * 128;
    int o0  = blockIdx.y * 128;
    int t = threadIdx.x;
    int wid = t >> 6, lane = t & 63;
    int wr = wid >> 1, wc = wid & 1;
    int lr = lane & 15, lk = lane >> 4;

    int rowi[2], qi[2];
    ushort8v ra[2], rb[2];
    #pragma unroll
    for (int i = 0; i < 2; ++i) { int id = t + i*256; rowi[i] = id >> 2; qi[i] = id & 3; }
    #pragma unroll
    for (int i = 0; i < 2; ++i) {
        ra[i] = *(const ushort8v*)&W1b[(size_t)(o0 + rowi[i]) * KCH + qi[i]*8];
        rb[i] = *(const ushort8v*)&HbT[(size_t)(pp0 + rowi[i]) * KCH + qi[i]*8];
    }

    f32x4 acc[4][4] = {};

    for (int c0 = 0; c0 < KCH; c0 += 32) {
        #pragma unroll
        for (int i = 0; i < 2; ++i) {
            *(ushort8v*)&As[rowi[i]][qi[i]*8] = ra[i];
            *(ushort8v*)&Bs[rowi[i]][qi[i]*8] = rb[i];
        }
        __syncthreads();
        int cn = (c0 + 32 < KCH) ? c0 + 32 : c0;   // last iter: redundant reload
        #pragma unroll
        for (int i = 0; i < 2; ++i) {
            ra[i] = *(const ushort8v*)&W1b[(size_t)(o0 + rowi[i]) * KCH + cn + qi[i]*8];
            rb[i] = *(const ushort8v*)&HbT[(size_t)(pp0 + rowi[i]) * KCH + cn + qi[i]*8];
        }
        bf16x8 af[4], bfr[4];
        #pragma unroll
        for (int m = 0; m < 4; ++m) af[m] = *(const bf16x8*)&As[wr*64 + m*16 + lr][lk*8];
        #pragma unroll
        for (int n = 0; n < 4; ++n) bfr[n] = *(const bf16x8*)&Bs[wc*64 + n*16 + lr][lk*8];
        #pragma unroll
        for (int m = 0; m < 4; ++m)
            #pragma unroll
            for (int n = 0; n < 4; ++n)
                acc[m][n] = __builtin_amdgcn_mfma_f32_16x16x32_bf16(af[m], bfr[n], acc[m][n], 0, 0, 0);
        __syncthreads();
    }
    #pragma unroll
    for (int n = 0; n < 4; ++n) {
        int p = pp0 + wc*64 + n*16 + lr;
        #pragma unroll
        for (int m = 0; m < 4; ++m) {
            int o = o0 + wr*64 + m*16 + lk*4;
            f32x4 v = acc[m][n];
            ushort4v w;
            w[0] = f2bf(v[0] + b1[o]);
            w[1] = f2bf(v[1] + b1[o+1]);
            w[2] = f2bf(v[2] + b1[o+2]);
            w[3] = f2bf(v[3] + b1[o+3]);
            *(ushort4v*)&h1T[(size_t)p * COUT + o] = w;
        }
    }
}

// ---------------------------------------------------------------------------
// K4: per-channel partial sums over h1T (unchanged)
// ---------------------------------------------------------------------------
__global__ __launch_bounds__(256) void stats_kernel(
    const unsigned short* __restrict__ h1T, float* __restrict__ psum, float* __restrict__ psq)
{
    __shared__ float ls[256][8];
    int seg = blockIdx.x, t = threadIdx.x;
    int col8 = (t & 31) * 8, rg = t >> 5;
    float s[8] = {}, q[8] = {};
    size_t base = (size_t)seg * SEGROWS * COUT;
    for (int p = rg; p < SEGROWS; p += 8) {
        ushort8v v = *(const ushort8v*)&h1T[base + (size_t)p * COUT + col8];
        #pragma unroll
        for (int j = 0; j < 8; ++j) { float f = bf2f(v[j]); s[j] += f; q[j] = fmaf(f, f, q[j]); }
    }
    #pragma unroll
    for (int j = 0; j < 8; ++j) ls[t][j] = s[j];
    __syncthreads();
    for (int off = 128; off >= 32; off >>= 1) {
        if (t < off) {
            #pragma unroll
            for (int j = 0; j < 8; ++j) ls[t][j] += ls[t + off][j];
        }
        __syncthreads();
    }
    if (t < 32) {
        #pragma unroll
        for (int j = 0; j < 8; ++j) psum[seg * COUT + t*8 + j] = ls[t][j];
    }
    __syncthreads();
    #pragma unroll
    for (int j = 0; j < 8; ++j) ls[t][j] = q[j];
    __syncthreads();
    for (int off = 128; off >= 32; off >>= 1) {
        if (t < off) {
            #pragma unroll
            for (int j = 0; j < 8; ++j) ls[t][j] += ls[t + off][j];
        }
        __syncthreads();
    }
    if (t < 32) {
        #pragma unroll
        for (int j = 0; j < 8; ++j) psq[seg * COUT + t*8 + j] = ls[t][j];
    }
}

__global__ __launch_bounds__(256) void bnfin_kernel(
    const float* __restrict__ psum, const float* __restrict__ psq,
    const float* __restrict__ gamma, const float* __restrict__ beta,
    float* __restrict__ bnscale, float* __restrict__ bnshift)
{
    int o = threadIdx.x;
    float S = 0.f, Q = 0.f;
    for (int s = 0; s < NSEG; ++s) { S += psum[s * COUT + o]; Q += psq[s * COUT + o]; }
    float mean = S * (1.0f / NP);
    float var  = Q * (1.0f / NP) - mean * mean;
    float sc = gamma[o] * rsqrtf(var + 1e-5f);
    bnscale[o] = sc;
    bnshift[o] = fmaf(-mean, sc, beta[o]);
}

// ---------------------------------------------------------------------------
// K5: GEMM2 (MFMA bf16), BN+ReLU fused at LDS-write, register prefetch,
// transposed epilogue: stage 64-o half-tiles in LDS (union'd over As/Bs),
// write 512 B coalesced float4 rows of out.
// ---------------------------------------------------------------------------
__global__ __launch_bounds__(256) void gemm2_kernel(
    const unsigned short* __restrict__ h1T, const unsigned short* __restrict__ W2b,
    const float* __restrict__ b2, const float* __restrict__ bnscale,
    const float* __restrict__ bnshift, float* __restrict__ out)
{
    __shared__ union {
        struct {
            __align__(16) unsigned short As[128][40];
            __align__(16) unsigned short Bs[128][40];
        } s;
        float eps[64][132];
    } u;
    __shared__ float scs[COUT], shs[COUT];
    int pp0 = blockIdx.x * 128;
    int o0  = blockIdx.y * 128;
    int t = threadIdx.x;
    scs[t] = bnscale[t]; shs[t] = bnshift[t];
    int wid = t >> 6, lane = t & 63;
    int wr = wid >> 1, wc = wid & 1;
    int lr = lane & 15, lk = lane >> 4;

    int rowi[2], qi[2];
    ushort8v ra[2], rb[2];
    #pragma unroll
    for (int i = 0; i < 2; ++i) { int id = t + i*256; rowi[i] = id >> 2; qi[i] = id & 3; }
    #pragma unroll
    for (int i = 0; i < 2; ++i) {
        ra[i] = *(const ushort8v*)&W2b[(size_t)(o0 + rowi[i]) * COUT + qi[i]*8];
        rb[i] = *(const ushort8v*)&h1T[(size_t)(pp0 + rowi[i]) * COUT + qi[i]*8];
    }
    f32x4 acc[4][4] = {};
    __syncthreads();

    for (int c0 = 0; c0 < COUT; c0 += 32) {
        #pragma unroll
        for (int i = 0; i < 2; ++i) {
            *(ushort8v*)&u.s.As[rowi[i]][qi[i]*8] = ra[i];
            ushort8v bv;
            #pragma unroll
            for (int j = 0; j < 8; ++j) {
                float f = fmaf(bf2f(rb[i][j]), scs[c0 + qi[i]*8 + j], shs[c0 + qi[i]*8 + j]);
                bv[j] = f2bf(fmaxf(f, 0.0f));
            }
            *(ushort8v*)&u.s.Bs[rowi[i]][qi[i]*8] = bv;
        }
        __syncthreads();
        int cn = (c0 + 32 < COUT) ? c0 + 32 : c0;
        #pragma unroll
        for (int i = 0; i < 2; ++i) {
            ra[i] = *(const ushort8v*)&W2b[(size_t)(o0 + rowi[i]) * COUT + cn + qi[i]*8];
            rb[i] = *(const ushort8v*)&h1T[(size_t)(pp0 + rowi[i]) * COUT + cn + qi[i]*8];
        }
        bf16x8 af[4], bfr[4];
        #pragma unroll
        for (int m = 0; m < 4; ++m) af[m] = *(const bf16x8*)&u.s.As[wr*64 + m*16 + lr][lk*8];
        #pragma unroll
        for (int n = 0; n < 4; ++n) bfr[n] = *(const bf16x8*)&u.s.Bs[wc*64 + n*16 + lr][lk*8];
        #pragma unroll
        for (int m = 0; m < 4; ++m)
            #pragma unroll
            for (int n = 0; n < 4; ++n)
                acc[m][n] = __builtin_amdgcn_mfma_f32_16x16x32_bf16(af[m], bfr[n], acc[m][n], 0, 0, 0);
        __syncthreads();
    }
    // ---- transposed epilogue ----
    int b  = pp0 >> 12;
    int n0 = pp0 & (NN - 1);
    float b2v[4][4];
    #pragma unroll
    for (int m = 0; m < 4; ++m)
        #pragma unroll
        for (int j = 0; j < 4; ++j)
            b2v[m][j] = b2[o0 + wr*64 + m*16 + lk*4 + j];
    #pragma unroll
    for (int ow = 0; ow < 2; ++ow) {
        if (wr == ow) {
            #pragma unroll
            for (int m = 0; m < 4; ++m)
                #pragma unroll
                for (int n = 0; n < 4; ++n) {
                    f32x4 v = acc[m][n];
                    int pl = wc*64 + n*16 + lr;
                    #pragma unroll
                    for (int j = 0; j < 4; ++j)
                        u.eps[m*16 + lk*4 + j][pl] = v[j] + b2v[m][j];
                }
        }
        __syncthreads();
        #pragma unroll
        for (int i = 0; i < 8; ++i) {
            int r  = (t >> 5) + i * 8;
            int c4 = (t & 31) * 4;
            float4 v = *(const float4*)&u.eps[r][c4];
            *(float4*)&out[((size_t)(b * COUT + o0 + ow*64 + r)) * NN + n0 + c4] = v;
        }
        __syncthreads();
    }
}

// ---------------------------------------------------------------------------
extern "C" void kernel_launch(void* const* d_in, const int* in_sizes, int n_in,
                              void* d_out, int out_size, void* d_ws, size_t ws_size,
                              hipStream_t stream)
{
    const float* pts   = (const float*)d_in[0];
    const float* pf    = (const float*)d_in[1];
    const float* cen   = (const float*)d_in[2];
    const float* cf    = (const float*)d_in[3];
    const float* W1    = (const float*)d_in[4];
    const float* b1    = (const float*)d_in[5];
    const float* gamma = (const float*)d_in[6];
    const float* beta  = (const float*)d_in[7];
    const float* W2    = (const float*)d_in[8];
    const float* b2    = (const float*)d_in[9];
    float* out = (float*)d_out;

    char* ws = (char*)d_ws;
    size_t off = 0;
    unsigned short* HbT = (unsigned short*)(ws + off); off += (size_t)NP * KCH * 2;
    unsigned short* h1T = (unsigned short*)(ws + off); off += (size_t)NP * COUT * 2;
    unsigned short* W1b = (unsigned short*)(ws + off); off += (size_t)COUT * KCH * 2;
    unsigned short* W2b = (unsigned short*)(ws + off); off += (size_t)COUT * COUT * 2;
    float* pdist   = (float*)(ws + off); off += (size_t)NP * NCHUNK * 3 * sizeof(float);
    int*   pidx    = (int*)(ws + off);   off += (size_t)NP * NCHUNK * 3 * sizeof(int);
    float* psum    = (float*)(ws + off); off += (size_t)NSEG * COUT * sizeof(float);
    float* psq     = (float*)(ws + off); off += (size_t)NSEG * COUT * sizeof(float);
    float* bnscale = (float*)(ws + off); off += 1024;
    float* bnshift = (float*)(ws + off); off += 1024;
    (void)ws_size; (void)in_sizes; (void)n_in; (void)out_size;

    hipLaunchKernelGGL(prep_kernel,     dim3(1664),              dim3(256), 0, stream,
                       pf, HbT, W1, W2, W1b, W2b);
    hipLaunchKernelGGL(knn_part_kernel, dim3(NP / 256, NCHUNK),  dim3(256), 0, stream,
                       pts, cen, pdist, pidx);
    hipLaunchKernelGGL(interp_kernel,   dim3(256, 8),            dim3(256), 0, stream,
                       cf, pdist, pidx, HbT);
    hipLaunchKernelGGL(gemm1_kernel,    dim3(NP / 128, 2),       dim3(256), 0, stream,
                       HbT, W1b, b1, h1T);
    hipLaunchKernelGGL(stats_kernel,    dim3(NSEG),              dim3(256), 0, stream,
                       h1T, psum, psq);
    hipLaunchKernelGGL(bnfin_kernel,    dim3(1),                 dim3(256), 0, stream,
                       psum, psq, gamma, beta, bnscale, bnshift);
    hipLaunchKernelGGL(gemm2_kernel,    dim3(NP / 128, 2),       dim3(256), 0, stream,
                       h1T, W2b, b2, bnscale, bnshift, out);
}

// Round 8
// 151.376 us; speedup vs baseline: 3.4713x; 1.1352x over previous
//
#include <hip/hip_runtime.h>

#define BB   16
#define NN   4096
#define MM   1024
#define CIN  256
#define CSK  128
#define COUT 256
#define KCH  384              // CIN + CSK
#define NP   65536            // BB * NN
#define NSEG2 512             // gemm1 px-blocks = stats segments
#define NCHUNK 8
#define MCH  (MM / NCHUNK)    // 128
#define CVB  32               // interp channel-slots per block

typedef __attribute__((ext_vector_type(8))) short bf16x8;
typedef __attribute__((ext_vector_type(4))) float f32x4;
typedef __attribute__((ext_vector_type(8))) unsigned short ushort8v;
typedef __attribute__((ext_vector_type(4))) unsigned short ushort4v;

static __device__ __forceinline__ unsigned short f2bf(float f) {
    unsigned u = __builtin_bit_cast(unsigned, f);
    u += 0x7fffu + ((u >> 16) & 1u);          // round-to-nearest-even
    return (unsigned short)(u >> 16);
}
static __device__ __forceinline__ float bf2f(unsigned short h) {
    unsigned u = ((unsigned)h) << 16;
    return __builtin_bit_cast(float, u);
}

// ---------------------------------------------------------------------------
// K0: prep = pf_t (blocks 0..1023) + convw (1024..1663) + cen4 (1664..1727)
// cen4[b*MM+m] = (x, y, z, x^2+y^2+z^2)
// ---------------------------------------------------------------------------
__global__ __launch_bounds__(256) void prep_kernel(
    const float* __restrict__ pf, unsigned short* __restrict__ HbT,
    const float* __restrict__ W1, const float* __restrict__ W2,
    unsigned short* __restrict__ W1b, unsigned short* __restrict__ W2b,
    const float* __restrict__ cen, float4* __restrict__ cen4)
{
    __shared__ float ls[64][129];
    int blk = blockIdx.x;
    int t = threadIdx.x;
    if (blk >= 1664) {
        int i = (blk - 1664) * 256 + t;        // 0..16383 = b*MM + m
        const float* cb = cen + (size_t)i * 3;
        float x = cb[0], y = cb[1], z = cb[2];
        cen4[i] = make_float4(x, y, z, x*x + y*y + z*z);
        return;
    }
    if (blk >= 1024) {
        int i = (blk - 1024) * 256 + t;
        if (i < COUT * KCH) W1b[i] = f2bf(W1[i]);
        else {
            int j = i - COUT * KCH;
            if (j < COUT * COUT) W2b[j] = f2bf(W2[j]);
        }
        return;
    }
    int b = blk >> 6, n0 = (blk & 63) * 64;
    const float* src = pf + (size_t)b * CSK * NN;
    #pragma unroll
    for (int i = 0; i < 32; ++i) {
        int id = t + i * 256;
        int c = id >> 6, nn = id & 63;
        ls[nn][c] = src[(size_t)c * NN + n0 + nn];
    }
    __syncthreads();
    int row = t & 63, ch = (t >> 6) * 32;
    unsigned short* dst = HbT + ((size_t)b * NN + n0 + row) * KCH + ch;
    #pragma unroll
    for (int g = 0; g < 4; ++g) {
        ushort8v w;
        #pragma unroll
        for (int j = 0; j < 8; ++j) w[j] = f2bf(ls[row][ch + g*8 + j]);
        *(ushort8v*)&dst[g*8] = w;
    }
}

// ---------------------------------------------------------------------------
// K1: partial KNN — 256 points x 128 centroids per block.
// Centroids read via wave-uniform index -> s_load_dwordx4 into SGPRs (no
// LDS, no VGPR staging). Distance: 5 VALU; select: min + 2x med3 for
// distances + 3 cmp + 5 cndmask for indices. Same strict-< fp32 semantics.
// ---------------------------------------------------------------------------
__global__ __launch_bounds__(256) void knn_part_kernel(
    const float* __restrict__ pts, const float4* __restrict__ cen4,
    float* __restrict__ pdist, int* __restrict__ pidx)
{
    int p0    = blockIdx.x * 256;
    int chunk = blockIdx.y;
    int b     = p0 >> 12;
    int m0    = chunk * MCH;
    const float4* cb4 = cen4 + (size_t)b * MM + m0;   // wave-uniform base

    int p = p0 + threadIdx.x;
    int n = p & (NN - 1);
    const float* pb = pts + (size_t)b * 3 * NN;
    float px = pb[3*n], py = pb[3*n+1], pz = pb[3*n+2];
    float pw = px*px + py*py + pz*pz;

    float d0 = 1e30f, d1 = 1e30f, d2v = 1e30f;
    int   i0 = 0, i1 = 0, i2 = 0;
    #pragma unroll 16
    for (int m = 0; m < MCH; ++m) {
        float4 c = cb4[m];                 // uniform -> scalar load
        float dot = px*c.x + py*c.y + pz*c.z;
        float d = (pw + c.w) - 2.0f * dot; // same expansion as reference
        bool c0 = d < d0, c1 = d < d1, c2 = d < d2v;
        int ni2 = c1 ? i1 : (c2 ? m : i2);
        int ni1 = c0 ? i0 : (c1 ? m : i1);
        int ni0 = c0 ? m  : i0;
        float nd1 = __builtin_amdgcn_fmed3f(d, d0, d1);
        float nd2 = __builtin_amdgcn_fmed3f(d, d1, d2v);
        d0 = fminf(d0, d);
        d1 = nd1; d2v = nd2;
        i0 = ni0; i1 = ni1; i2 = ni2;
    }
    int base = (p * NCHUNK + chunk) * 3;
    pdist[base] = d0;      pdist[base+1] = d1;      pdist[base+2] = d2v;
    pidx[base]  = m0 + i0; pidx[base+1]  = m0 + i1; pidx[base+2]  = m0 + i2;
}

// ---------------------------------------------------------------------------
// K2: interp + inline KNN-merge + scramble (unchanged R7).
// ---------------------------------------------------------------------------
__global__ __launch_bounds__(256) void interp_kernel(
    const float* __restrict__ cf, const float* __restrict__ pdist,
    const int* __restrict__ pidx, unsigned short* __restrict__ HbT)
{
    __shared__ int   li[CVB][3];
    __shared__ float lw[CVB][3];
    __shared__ unsigned short tile[CVB][258];
    int bh = blockIdx.x;
    int b = bh >> 4, hi = bh & 15;
    int ch = blockIdx.y;
    int t = threadIdx.x;
    if (t < CVB) {
        int P = b * NN + (ch * CVB + t) * 16 + hi;
        float d0 = 1e30f, d1 = 1e30f, d2v = 1e30f;
        int   i0 = 0, i1 = 0, i2 = 0;
        int base = P * NCHUNK * 3;
        #pragma unroll
        for (int c = 0; c < NCHUNK * 3; ++c) {
            float d = pdist[base + c];
            int   i = pidx[base + c];
            bool c2 = d < d2v, c1 = d < d1, c0 = d < d0;
            d2v = c1 ? d1 : (c2 ? d : d2v);
            i2  = c1 ? i1 : (c2 ? i : i2);
            d1  = c0 ? d0 : (c1 ? d : d1);
            i1  = c0 ? i0 : (c1 ? i : i1);
            d0  = c0 ? d  : d0;
            i0  = c0 ? i  : i0;
        }
        float w0 = 1.0f / fmaxf(d0,  1e-16f);
        float w1 = 1.0f / fmaxf(d1,  1e-16f);
        float w2 = 1.0f / fmaxf(d2v, 1e-16f);
        float inv = 1.0f / (w0 + w1 + w2);
        li[t][0] = i0;     li[t][1] = i1;     li[t][2] = i2;
        lw[t][0] = w0*inv; lw[t][1] = w1*inv; lw[t][2] = w2*inv;
    }
    __syncthreads();
    const float* cfb = cf + (size_t)b * MM * CIN;
    #pragma unroll 4
    for (int cv = 0; cv < CVB; ++cv) {
        float v = lw[cv][0] * cfb[(size_t)li[cv][0] * CIN + t]
                + lw[cv][1] * cfb[(size_t)li[cv][1] * CIN + t]
                + lw[cv][2] * cfb[(size_t)li[cv][2] * CIN + t];
        tile[cv][t] = f2bf(v);
    }
    __syncthreads();
    size_t dstbase = ((size_t)b * NN + hi * 256 + t) * KCH + CSK + ch * CVB;
    #pragma unroll
    for (int g = 0; g < CVB / 8; ++g) {
        ushort8v w;
        #pragma unroll
        for (int j = 0; j < 8; ++j) w[j] = tile[g*8 + j][t];
        *(ushort8v*)&HbT[dstbase + g*8] = w;
    }
}

// ---------------------------------------------------------------------------
// K3: GEMM1 (MFMA bf16) + fused BN partial stats.
// psum/psq layout: [o][NSEG2] with seg = blockIdx.x.
// ---------------------------------------------------------------------------
__global__ __launch_bounds__(256) void gemm1_kernel(
    const unsigned short* __restrict__ HbT, const unsigned short* __restrict__ W1b,
    const float* __restrict__ b1, unsigned short* __restrict__ h1T,
    float* __restrict__ psum, float* __restrict__ psq)
{
    __shared__ __align__(16) unsigned short As[128][40];
    __shared__ __align__(16) unsigned short Bs[128][40];
    int pp0 = blockIdx.x * 128;
    int o0  = blockIdx.y * 128;
    int t = threadIdx.x;
    int wid = t >> 6, lane = t & 63;
    int wr = wid >> 1, wc = wid & 1;
    int lr = lane & 15, lk = lane >> 4;

    int rowi[2], qi[2];
    ushort8v ra[2], rb[2];
    #pragma unroll
    for (int i = 0; i < 2; ++i) { int id = t + i*256; rowi[i] = id >> 2; qi[i] = id & 3; }
    #pragma unroll
    for (int i = 0; i < 2; ++i) {
        ra[i] = *(const ushort8v*)&W1b[(size_t)(o0 + rowi[i]) * KCH + qi[i]*8];
        rb[i] = *(const ushort8v*)&HbT[(size_t)(pp0 + rowi[i]) * KCH + qi[i]*8];
    }

    f32x4 acc[4][4] = {};

    for (int c0 = 0; c0 < KCH; c0 += 32) {
        #pragma unroll
        for (int i = 0; i < 2; ++i) {
            *(ushort8v*)&As[rowi[i]][qi[i]*8] = ra[i];
            *(ushort8v*)&Bs[rowi[i]][qi[i]*8] = rb[i];
        }
        __syncthreads();
        int cn = (c0 + 32 < KCH) ? c0 + 32 : c0;
        #pragma unroll
        for (int i = 0; i < 2; ++i) {
            ra[i] = *(const ushort8v*)&W1b[(size_t)(o0 + rowi[i]) * KCH + cn + qi[i]*8];
            rb[i] = *(const ushort8v*)&HbT[(size_t)(pp0 + rowi[i]) * KCH + cn + qi[i]*8];
        }
        bf16x8 af[4], bfr[4];
        #pragma unroll
        for (int m = 0; m < 4; ++m) af[m] = *(const bf16x8*)&As[wr*64 + m*16 + lr][lk*8];
        #pragma unroll
        for (int n = 0; n < 4; ++n) bfr[n] = *(const bf16x8*)&Bs[wc*64 + n*16 + lr][lk*8];
        #pragma unroll
        for (int m = 0; m < 4; ++m)
            #pragma unroll
            for (int n = 0; n < 4; ++n)
                acc[m][n] = __builtin_amdgcn_mfma_f32_16x16x32_bf16(af[m], bfr[n], acc[m][n], 0, 0, 0);
        __syncthreads();
    }
    // epilogue: h1T write + per-(m,j) partial sums over n (p-direction)
    float sprt[4][4] = {{0.f}}, qprt[4][4] = {{0.f}};
    #pragma unroll
    for (int n = 0; n < 4; ++n) {
        int p = pp0 + wc*64 + n*16 + lr;
        #pragma unroll
        for (int m = 0; m < 4; ++m) {
            int o = o0 + wr*64 + m*16 + lk*4;
            f32x4 v = acc[m][n];
            ushort4v w;
            #pragma unroll
            for (int j = 0; j < 4; ++j) {
                float f = v[j] + b1[o + j];
                w[j] = f2bf(f);
                float r = bf2f(w[j]);
                sprt[m][j] += r;
                qprt[m][j] = fmaf(r, r, qprt[m][j]);
            }
            *(ushort4v*)&h1T[(size_t)p * COUT + o] = w;
        }
    }
    // reduce over the 16 lanes (lr) of each lk-group
    #pragma unroll
    for (int m = 0; m < 4; ++m)
        #pragma unroll
        for (int j = 0; j < 4; ++j) {
            float s = sprt[m][j], q = qprt[m][j];
            #pragma unroll
            for (int off = 1; off < 16; off <<= 1) {
                s += __shfl_xor(s, off, 64);
                q += __shfl_xor(q, off, 64);
            }
            sprt[m][j] = s; qprt[m][j] = q;
        }
    // stage per-wave partials in (dead) As LDS, combine wc halves, write
    float* sred = (float*)As;          // [2][128] s then [2][128] q
    float* qred = sred + 256;
    if (lr == 0) {
        #pragma unroll
        for (int m = 0; m < 4; ++m)
            #pragma unroll
            for (int j = 0; j < 4; ++j) {
                int ol = wr*64 + m*16 + lk*4 + j;
                sred[wc*128 + ol] = sprt[m][j];
                qred[wc*128 + ol] = qprt[m][j];
            }
    }
    __syncthreads();
    if (t < 128) {
        float S = sred[t] + sred[128 + t];
        float Q = qred[t] + qred[128 + t];
        psum[(size_t)(o0 + t) * NSEG2 + blockIdx.x] = S;
        psq [(size_t)(o0 + t) * NSEG2 + blockIdx.x] = Q;
    }
}

// ---------------------------------------------------------------------------
// K4: BN finalize — one block per channel, tree-reduce 512 segments.
// ---------------------------------------------------------------------------
__global__ __launch_bounds__(256) void bnfin_kernel(
    const float* __restrict__ psum, const float* __restrict__ psq,
    const float* __restrict__ gamma, const float* __restrict__ beta,
    float* __restrict__ bnscale, float* __restrict__ bnshift)
{
    __shared__ float rs[256], rq[256];
    int o = blockIdx.x, t = threadIdx.x;
    rs[t] = psum[(size_t)o * NSEG2 + t] + psum[(size_t)o * NSEG2 + 256 + t];
    rq[t] = psq [(size_t)o * NSEG2 + t] + psq [(size_t)o * NSEG2 + 256 + t];
    __syncthreads();
    for (int off = 128; off > 0; off >>= 1) {
        if (t < off) { rs[t] += rs[t + off]; rq[t] += rq[t + off]; }
        __syncthreads();
    }
    if (t == 0) {
        float mean = rs[0] * (1.0f / NP);
        float var  = rq[0] * (1.0f / NP) - mean * mean;
        float sc = gamma[o] * rsqrtf(var + 1e-5f);
        bnscale[o] = sc;
        bnshift[o] = fmaf(-mean, sc, beta[o]);
    }
}

// ---------------------------------------------------------------------------
// K5: GEMM2 (MFMA bf16), BN+ReLU fused at LDS-write, register prefetch,
// transposed epilogue through LDS (unchanged R7).
// ---------------------------------------------------------------------------
__global__ __launch_bounds__(256) void gemm2_kernel(
    const unsigned short* __restrict__ h1T, const unsigned short* __restrict__ W2b,
    const float* __restrict__ b2, const float* __restrict__ bnscale,
    const float* __restrict__ bnshift, float* __restrict__ out)
{
    __shared__ union {
        struct {
            __align__(16) unsigned short As[128][40];
            __align__(16) unsigned short Bs[128][40];
        } s;
        float eps[64][132];
    } u;
    __shared__ float scs[COUT], shs[COUT];
    int pp0 = blockIdx.x * 128;
    int o0  = blockIdx.y * 128;
    int t = threadIdx.x;
    scs[t] = bnscale[t]; shs[t] = bnshift[t];
    int wid = t >> 6, lane = t & 63;
    int wr = wid >> 1, wc = wid & 1;
    int lr = lane & 15, lk = lane >> 4;

    int rowi[2], qi[2];
    ushort8v ra[2], rb[2];
    #pragma unroll
    for (int i = 0; i < 2; ++i) { int id = t + i*256; rowi[i] = id >> 2; qi[i] = id & 3; }
    #pragma unroll
    for (int i = 0; i < 2; ++i) {
        ra[i] = *(const ushort8v*)&W2b[(size_t)(o0 + rowi[i]) * COUT + qi[i]*8];
        rb[i] = *(const ushort8v*)&h1T[(size_t)(pp0 + rowi[i]) * COUT + qi[i]*8];
    }
    f32x4 acc[4][4] = {};
    __syncthreads();

    for (int c0 = 0; c0 < COUT; c0 += 32) {
        #pragma unroll
        for (int i = 0; i < 2; ++i) {
            *(ushort8v*)&u.s.As[rowi[i]][qi[i]*8] = ra[i];
            ushort8v bv;
            #pragma unroll
            for (int j = 0; j < 8; ++j) {
                float f = fmaf(bf2f(rb[i][j]), scs[c0 + qi[i]*8 + j], shs[c0 + qi[i]*8 + j]);
                bv[j] = f2bf(fmaxf(f, 0.0f));
            }
            *(ushort8v*)&u.s.Bs[rowi[i]][qi[i]*8] = bv;
        }
        __syncthreads();
        int cn = (c0 + 32 < COUT) ? c0 + 32 : c0;
        #pragma unroll
        for (int i = 0; i < 2; ++i) {
            ra[i] = *(const ushort8v*)&W2b[(size_t)(o0 + rowi[i]) * COUT + cn + qi[i]*8];
            rb[i] = *(const ushort8v*)&h1T[(size_t)(pp0 + rowi[i]) * COUT + cn + qi[i]*8];
        }
        bf16x8 af[4], bfr[4];
        #pragma unroll
        for (int m = 0; m < 4; ++m) af[m] = *(const bf16x8*)&u.s.As[wr*64 + m*16 + lr][lk*8];
        #pragma unroll
        for (int n = 0; n < 4; ++n) bfr[n] = *(const bf16x8*)&u.s.Bs[wc*64 + n*16 + lr][lk*8];
        #pragma unroll
        for (int m = 0; m < 4; ++m)
            #pragma unroll
            for (int n = 0; n < 4; ++n)
                acc[m][n] = __builtin_amdgcn_mfma_f32_16x16x32_bf16(af[m], bfr[n], acc[m][n], 0, 0, 0);
        __syncthreads();
    }
    // ---- transposed epilogue ----
    int b  = pp0 >> 12;
    int n0 = pp0 & (NN - 1);
    float b2v[4][4];
    #pragma unroll
    for (int m = 0; m < 4; ++m)
        #pragma unroll
        for (int j = 0; j < 4; ++j)
            b2v[m][j] = b2[o0 + wr*64 + m*16 + lk*4 + j];
    #pragma unroll
    for (int ow = 0; ow < 2; ++ow) {
        if (wr == ow) {
            #pragma unroll
            for (int m = 0; m < 4; ++m)
                #pragma unroll
                for (int n = 0; n < 4; ++n) {
                    f32x4 v = acc[m][n];
                    int pl = wc*64 + n*16 + lr;
                    #pragma unroll
                    for (int j = 0; j < 4; ++j)
                        u.eps[m*16 + lk*4 + j][pl] = v[j] + b2v[m][j];
                }
        }
        __syncthreads();
        #pragma unroll
        for (int i = 0; i < 8; ++i) {
            int r  = (t >> 5) + i * 8;
            int c4 = (t & 31) * 4;
            float4 v = *(const float4*)&u.eps[r][c4];
            *(float4*)&out[((size_t)(b * COUT + o0 + ow*64 + r)) * NN + n0 + c4] = v;
        }
        __syncthreads();
    }
}

// ---------------------------------------------------------------------------
extern "C" void kernel_launch(void* const* d_in, const int* in_sizes, int n_in,
                              void* d_out, int out_size, void* d_ws, size_t ws_size,
                              hipStream_t stream)
{
    const float* pts   = (const float*)d_in[0];
    const float* pf    = (const float*)d_in[1];
    const float* cen   = (const float*)d_in[2];
    const float* cf    = (const float*)d_in[3];
    const float* W1    = (const float*)d_in[4];
    const float* b1    = (const float*)d_in[5];
    const float* gamma = (const float*)d_in[6];
    const float* beta  = (const float*)d_in[7];
    const float* W2    = (const float*)d_in[8];
    const float* b2    = (const float*)d_in[9];
    float* out = (float*)d_out;

    char* ws = (char*)d_ws;
    size_t off = 0;
    unsigned short* HbT = (unsigned short*)(ws + off); off += (size_t)NP * KCH * 2;
    unsigned short* h1T = (unsigned short*)(ws + off); off += (size_t)NP * COUT * 2;
    unsigned short* W1b = (unsigned short*)(ws + off); off += (size_t)COUT * KCH * 2;
    unsigned short* W2b = (unsigned short*)(ws + off); off += (size_t)COUT * COUT * 2;
    float* pdist   = (float*)(ws + off); off += (size_t)NP * NCHUNK * 3 * sizeof(float);
    int*   pidx    = (int*)(ws + off);   off += (size_t)NP * NCHUNK * 3 * sizeof(int);
    float4* cen4   = (float4*)(ws + off); off += (size_t)BB * MM * sizeof(float4);
    float* psum    = (float*)(ws + off); off += (size_t)COUT * NSEG2 * sizeof(float);
    float* psq     = (float*)(ws + off); off += (size_t)COUT * NSEG2 * sizeof(float);
    float* bnscale = (float*)(ws + off); off += 1024;
    float* bnshift = (float*)(ws + off); off += 1024;
    (void)ws_size; (void)in_sizes; (void)n_in; (void)out_size;

    hipLaunchKernelGGL(prep_kernel,     dim3(1728),              dim3(256), 0, stream,
                       pf, HbT, W1, W2, W1b, W2b, cen, cen4);
    hipLaunchKernelGGL(knn_part_kernel, dim3(NP / 256, NCHUNK),  dim3(256), 0, stream,
                       pts, cen4, pdist, pidx);
    hipLaunchKernelGGL(interp_kernel,   dim3(256, 8),            dim3(256), 0, stream,
                       cf, pdist, pidx, HbT);
    hipLaunchKernelGGL(gemm1_kernel,    dim3(NP / 128, 2),       dim3(256), 0, stream,
                       HbT, W1b, b1, h1T, psum, psq);
    hipLaunchKernelGGL(bnfin_kernel,    dim3(COUT),              dim3(256), 0, stream,
                       psum, psq, gamma, beta, bnscale, bnshift);
    hipLaunchKernelGGL(gemm2_kernel,    dim3(NP / 128, 2),       dim3(256), 0, stream,
                       h1T, W2b, b2, bnscale, bnshift, out);
}

// Round 9
// 134.168 us; speedup vs baseline: 3.9166x; 1.1283x over previous
//
#include <hip/hip_runtime.h>

#define BB   16
#define NN   4096
#define MM   1024
#define CIN  256
#define CSK  128
#define COUT 256
#define KCH  384              // CIN + CSK
#define NP   65536            // BB * NN
#define NSEG2 512             // gemm1 px-blocks = stats segments
#define NCHUNK 8
#define MCH  (MM / NCHUNK)    // 128
#define CVB  32               // interp channel-slots per block

typedef __attribute__((ext_vector_type(8))) short bf16x8;
typedef __attribute__((ext_vector_type(4))) float f32x4;
typedef __attribute__((ext_vector_type(8))) unsigned short ushort8v;
typedef __attribute__((ext_vector_type(4))) unsigned short ushort4v;

static __device__ __forceinline__ unsigned short f2bf(float f) {
    unsigned u = __builtin_bit_cast(unsigned, f);
    u += 0x7fffu + ((u >> 16) & 1u);          // round-to-nearest-even
    return (unsigned short)(u >> 16);
}
static __device__ __forceinline__ float bf2f(unsigned short h) {
    unsigned u = ((unsigned)h) << 16;
    return __builtin_bit_cast(float, u);
}

// ---------------------------------------------------------------------------
// K0 megakernel:
//   blocks 0..2047    : partial KNN (256 points x 128 centroids) — long pole
//   blocks 2048..4095 : cf fp32 -> bf16 (cfb), 8 elems/thread
//   blocks 4096..6143 : pf transpose 64n x 64c -> HbT bf16
//   blocks 6144..6783 : W1/W2 -> bf16
// Memory-bound prep co-resides with VALU-bound KNN and fills its stalls.
// ---------------------------------------------------------------------------
__global__ __launch_bounds__(256) void megak_kernel(
    const float* __restrict__ pts, const float* __restrict__ cen,
    float* __restrict__ pdist, int* __restrict__ pidx,
    const float* __restrict__ cf, unsigned short* __restrict__ cfb,
    const float* __restrict__ pf, unsigned short* __restrict__ HbT,
    const float* __restrict__ W1, const float* __restrict__ W2,
    unsigned short* __restrict__ W1b, unsigned short* __restrict__ W2b)
{
    __shared__ union { float4 sc[MCH]; float ls[64][65]; } su;
    int blk = blockIdx.x;
    int t = threadIdx.x;

    if (blk < 2048) {
        // ---------------- KNN partial (R8 semantics, LDS-staged centroids)
        int p0    = (blk >> 3) * 256;
        int chunk = blk & 7;
        int b     = p0 >> 12;
        int m0    = chunk * MCH;
        const float* cb = cen + (size_t)b * 3 * MM + 3 * m0;
        if (t < MCH) {
            float x = cb[3*t], y = cb[3*t+1], z = cb[3*t+2];
            su.sc[t] = make_float4(x, y, z, x*x + y*y + z*z);
        }
        __syncthreads();

        int p = p0 + t;
        int n = p & (NN - 1);
        const float* pb = pts + (size_t)b * 3 * NN;
        float px = pb[3*n], py = pb[3*n+1], pz = pb[3*n+2];
        float pw = px*px + py*py + pz*pz;

        float d0 = 1e30f, d1 = 1e30f, d2v = 1e30f;
        int   i0 = 0, i1 = 0, i2 = 0;
        #pragma unroll 16
        for (int m = 0; m < MCH; ++m) {
            float4 c = su.sc[m];
            float dot = px*c.x + py*c.y + pz*c.z;
            float d = (pw + c.w) - 2.0f * dot;   // same expansion as reference
            bool c0 = d < d0, c1 = d < d1, c2 = d < d2v;
            int ni2 = c1 ? i1 : (c2 ? m : i2);
            int ni1 = c0 ? i0 : (c1 ? m : i1);
            int ni0 = c0 ? m  : i0;
            float nd1 = __builtin_amdgcn_fmed3f(d, d0, d1);
            float nd2 = __builtin_amdgcn_fmed3f(d, d1, d2v);
            d0 = fminf(d0, d);
            d1 = nd1; d2v = nd2;
            i0 = ni0; i1 = ni1; i2 = ni2;
        }
        int base = (p * NCHUNK + chunk) * 3;
        pdist[base] = d0;      pdist[base+1] = d1;      pdist[base+2] = d2v;
        pidx[base]  = m0 + i0; pidx[base+1]  = m0 + i1; pidx[base+2]  = m0 + i2;
        return;
    }
    if (blk < 4096) {
        // ---------------- cf -> bf16
        int g = blk - 2048;
        size_t e8 = ((size_t)g * 256 + t) * 8;   // 2048*256*8 = 4.19M = BB*MM*CIN
        const float4* cf4 = (const float4*)(cf + e8);
        float4 a = cf4[0], b4 = cf4[1];
        ushort8v w;
        w[0]=f2bf(a.x); w[1]=f2bf(a.y); w[2]=f2bf(a.z); w[3]=f2bf(a.w);
        w[4]=f2bf(b4.x); w[5]=f2bf(b4.y); w[6]=f2bf(b4.z); w[7]=f2bf(b4.w);
        *(ushort8v*)&cfb[e8] = w;
        return;
    }
    if (blk < 6144) {
        // ---------------- pf transpose: 64 n x 64 c tile
        int g = blk - 4096;          // 0..2047
        int b = g >> 7;
        int r = g & 127;
        int n0 = (r >> 1) * 64;
        int c0 = (r & 1) * 64;
        const float* src = pf + (size_t)b * CSK * NN;
        #pragma unroll
        for (int i = 0; i < 16; ++i) {
            int id = t + i * 256;
            int cc = id >> 6, nn = id & 63;
            su.ls[nn][cc] = src[(size_t)(c0 + cc) * NN + n0 + nn];
        }
        __syncthreads();
        int row = t & 63, ch0 = (t >> 6) * 16;
        unsigned short* dst = HbT + ((size_t)b * NN + n0 + row) * KCH + c0 + ch0;
        #pragma unroll
        for (int g2 = 0; g2 < 2; ++g2) {
            ushort8v w;
            #pragma unroll
            for (int j = 0; j < 8; ++j) w[j] = f2bf(su.ls[row][ch0 + g2*8 + j]);
            *(ushort8v*)&dst[g2*8] = w;
        }
        return;
    }
    // ---------------- W1/W2 -> bf16
    {
        int i = (blk - 6144) * 256 + t;
        if (i < COUT * KCH) W1b[i] = f2bf(W1[i]);
        else {
            int j = i - COUT * KCH;
            if (j < COUT * COUT) W2b[j] = f2bf(W2[j]);
        }
    }
}

// ---------------------------------------------------------------------------
// K1: interp + inline KNN-merge + scramble. bf16 cf gathers; XCD-aware
// decode: batch pair (2 MB slab) pinned to one XCD's L2.
// ---------------------------------------------------------------------------
__global__ __launch_bounds__(256) void interp_kernel(
    const unsigned short* __restrict__ cfb, const float* __restrict__ pdist,
    const int* __restrict__ pidx, unsigned short* __restrict__ HbT)
{
    __shared__ int   li[CVB][3];
    __shared__ float lw[CVB][3];
    __shared__ unsigned short tile[CVB][258];
    // decode so blocks of batches {2x,2x+1} land on XCD x (round-robin heuristic)
    int xcd = blockIdx.x & 7;
    int j   = blockIdx.x >> 3;            // 0..255
    int b   = xcd * 2 + (j >> 7);
    int rem = j & 127;
    int hi  = rem >> 3;
    int ch  = rem & 7;
    int t = threadIdx.x;
    if (t < CVB) {
        int P = b * NN + (ch * CVB + t) * 16 + hi;
        float d0 = 1e30f, d1 = 1e30f, d2v = 1e30f;
        int   i0 = 0, i1 = 0, i2 = 0;
        int base = P * NCHUNK * 3;
        #pragma unroll
        for (int c = 0; c < NCHUNK * 3; ++c) {
            float d = pdist[base + c];
            int   i = pidx[base + c];
            bool c2 = d < d2v, c1 = d < d1, c0 = d < d0;
            d2v = c1 ? d1 : (c2 ? d : d2v);
            i2  = c1 ? i1 : (c2 ? i : i2);
            d1  = c0 ? d0 : (c1 ? d : d1);
            i1  = c0 ? i0 : (c1 ? i : i1);
            d0  = c0 ? d  : d0;
            i0  = c0 ? i  : i0;
        }
        float w0 = 1.0f / fmaxf(d0,  1e-16f);
        float w1 = 1.0f / fmaxf(d1,  1e-16f);
        float w2 = 1.0f / fmaxf(d2v, 1e-16f);
        float inv = 1.0f / (w0 + w1 + w2);
        li[t][0] = i0;     li[t][1] = i1;     li[t][2] = i2;
        lw[t][0] = w0*inv; lw[t][1] = w1*inv; lw[t][2] = w2*inv;
    }
    __syncthreads();
    const unsigned short* cfbb = cfb + (size_t)b * MM * CIN;
    #pragma unroll 4
    for (int cv = 0; cv < CVB; ++cv) {
        float v = lw[cv][0] * bf2f(cfbb[(size_t)li[cv][0] * CIN + t])
                + lw[cv][1] * bf2f(cfbb[(size_t)li[cv][1] * CIN + t])
                + lw[cv][2] * bf2f(cfbb[(size_t)li[cv][2] * CIN + t]);
        tile[cv][t] = f2bf(v);
    }
    __syncthreads();
    size_t dstbase = ((size_t)b * NN + hi * 256 + t) * KCH + CSK + ch * CVB;
    #pragma unroll
    for (int g = 0; g < CVB / 8; ++g) {
        ushort8v w;
        #pragma unroll
        for (int j2 = 0; j2 < 8; ++j2) w[j2] = tile[g*8 + j2][t];
        *(ushort8v*)&HbT[dstbase + g*8] = w;
    }
}

// ---------------------------------------------------------------------------
// K2: GEMM1 (MFMA bf16) + fused BN partial stats + coalesced LDS epilogue.
// ---------------------------------------------------------------------------
__global__ __launch_bounds__(256) void gemm1_kernel(
    const unsigned short* __restrict__ HbT, const unsigned short* __restrict__ W1b,
    const float* __restrict__ b1, unsigned short* __restrict__ h1T,
    float* __restrict__ psum, float* __restrict__ psq)
{
    __shared__ union {
        struct {
            __align__(16) unsigned short As[128][40];
            __align__(16) unsigned short Bs[128][40];
        } s;
        struct {
            __align__(16) unsigned short eps[64][136];
            float red[512];
        } e;
    } u;
    int pp0 = blockIdx.x * 128;
    int o0  = blockIdx.y * 128;
    int t = threadIdx.x;
    int wid = t >> 6, lane = t & 63;
    int wr = wid >> 1, wc = wid & 1;
    int lr = lane & 15, lk = lane >> 4;

    int rowi[2], qi[2];
    ushort8v ra[2], rb[2];
    #pragma unroll
    for (int i = 0; i < 2; ++i) { int id = t + i*256; rowi[i] = id >> 2; qi[i] = id & 3; }
    #pragma unroll
    for (int i = 0; i < 2; ++i) {
        ra[i] = *(const ushort8v*)&W1b[(size_t)(o0 + rowi[i]) * KCH + qi[i]*8];
        rb[i] = *(const ushort8v*)&HbT[(size_t)(pp0 + rowi[i]) * KCH + qi[i]*8];
    }

    f32x4 acc[4][4] = {};

    for (int c0 = 0; c0 < KCH; c0 += 32) {
        #pragma unroll
        for (int i = 0; i < 2; ++i) {
            *(ushort8v*)&u.s.As[rowi[i]][qi[i]*8] = ra[i];
            *(ushort8v*)&u.s.Bs[rowi[i]][qi[i]*8] = rb[i];
        }
        __syncthreads();
        int cn = (c0 + 32 < KCH) ? c0 + 32 : c0;
        #pragma unroll
        for (int i = 0; i < 2; ++i) {
            ra[i] = *(const ushort8v*)&W1b[(size_t)(o0 + rowi[i]) * KCH + cn + qi[i]*8];
            rb[i] = *(const ushort8v*)&HbT[(size_t)(pp0 + rowi[i]) * KCH + cn + qi[i]*8];
        }
        bf16x8 af[4], bfr[4];
        #pragma unroll
        for (int m = 0; m < 4; ++m) af[m] = *(const bf16x8*)&u.s.As[wr*64 + m*16 + lr][lk*8];
        #pragma unroll
        for (int n = 0; n < 4; ++n) bfr[n] = *(const bf16x8*)&u.s.Bs[wc*64 + n*16 + lr][lk*8];
        #pragma unroll
        for (int m = 0; m < 4; ++m)
            #pragma unroll
            for (int n = 0; n < 4; ++n)
                acc[m][n] = __builtin_amdgcn_mfma_f32_16x16x32_bf16(af[m], bfr[n], acc[m][n], 0, 0, 0);
        __syncthreads();
    }
    // ---- epilogue: bias + bf16 round + stats, then coalesced store via LDS
    float bb[4][4];
    #pragma unroll
    for (int m = 0; m < 4; ++m)
        #pragma unroll
        for (int j = 0; j < 4; ++j)
            bb[m][j] = b1[o0 + wr*64 + m*16 + lk*4 + j];
    float sprt[4][4] = {{0.f}}, qprt[4][4] = {{0.f}};
    #pragma unroll
    for (int pw = 0; pw < 2; ++pw) {
        if (wc == pw) {
            #pragma unroll
            for (int n = 0; n < 4; ++n) {
                int r = n*16 + lr;
                #pragma unroll
                for (int m = 0; m < 4; ++m) {
                    f32x4 v = acc[m][n];
                    ushort4v w;
                    #pragma unroll
                    for (int j = 0; j < 4; ++j) {
                        float f = v[j] + bb[m][j];
                        w[j] = f2bf(f);
                        float rr = bf2f(w[j]);
                        sprt[m][j] += rr;
                        qprt[m][j] = fmaf(rr, rr, qprt[m][j]);
                    }
                    *(ushort4v*)&u.e.eps[r][wr*64 + m*16 + lk*4] = w;
                }
            }
        }
        __syncthreads();
        {
            int r = t >> 2, seg = t & 3;
            size_t gbase = ((size_t)(pp0 + pw*64 + r)) * COUT + o0 + seg * 32;
            #pragma unroll
            for (int k = 0; k < 4; ++k) {
                ushort8v vv = *(const ushort8v*)&u.e.eps[r][seg*32 + k*8];
                *(ushort8v*)&h1T[gbase + k*8] = vv;
            }
        }
        __syncthreads();
    }
    // ---- stats reduce (identical semantics to R8)
    #pragma unroll
    for (int m = 0; m < 4; ++m)
        #pragma unroll
        for (int j = 0; j < 4; ++j) {
            float s = sprt[m][j], q = qprt[m][j];
            #pragma unroll
            for (int off = 1; off < 16; off <<= 1) {
                s += __shfl_xor(s, off, 64);
                q += __shfl_xor(q, off, 64);
            }
            sprt[m][j] = s; qprt[m][j] = q;
        }
    if (lr == 0) {
        #pragma unroll
        for (int m = 0; m < 4; ++m)
            #pragma unroll
            for (int j = 0; j < 4; ++j) {
                int ol = wr*64 + m*16 + lk*4 + j;
                u.e.red[wc*128 + ol]       = sprt[m][j];
                u.e.red[256 + wc*128 + ol] = qprt[m][j];
            }
    }
    __syncthreads();
    if (t < 128) {
        float S = u.e.red[t] + u.e.red[128 + t];
        float Q = u.e.red[256 + t] + u.e.red[384 + t];
        psum[(size_t)(o0 + t) * NSEG2 + blockIdx.x] = S;
        psq [(size_t)(o0 + t) * NSEG2 + blockIdx.x] = Q;
    }
}

// ---------------------------------------------------------------------------
// K3: BN finalize — one block per channel, tree-reduce 512 segments.
// ---------------------------------------------------------------------------
__global__ __launch_bounds__(256) void bnfin_kernel(
    const float* __restrict__ psum, const float* __restrict__ psq,
    const float* __restrict__ gamma, const float* __restrict__ beta,
    float* __restrict__ bnscale, float* __restrict__ bnshift)
{
    __shared__ float rs[256], rq[256];
    int o = blockIdx.x, t = threadIdx.x;
    rs[t] = psum[(size_t)o * NSEG2 + t] + psum[(size_t)o * NSEG2 + 256 + t];
    rq[t] = psq [(size_t)o * NSEG2 + t] + psq [(size_t)o * NSEG2 + 256 + t];
    __syncthreads();
    for (int off = 128; off > 0; off >>= 1) {
        if (t < off) { rs[t] += rs[t + off]; rq[t] += rq[t + off]; }
        __syncthreads();
    }
    if (t == 0) {
        float mean = rs[0] * (1.0f / NP);
        float var  = rq[0] * (1.0f / NP) - mean * mean;
        float sc = gamma[o] * rsqrtf(var + 1e-5f);
        bnscale[o] = sc;
        bnshift[o] = fmaf(-mean, sc, beta[o]);
    }
}

// ---------------------------------------------------------------------------
// K4: GEMM2 (MFMA bf16), BN+ReLU fused at LDS-write, register prefetch,
// transposed epilogue through LDS (unchanged R8).
// ---------------------------------------------------------------------------
__global__ __launch_bounds__(256) void gemm2_kernel(
    const unsigned short* __restrict__ h1T, const unsigned short* __restrict__ W2b,
    const float* __restrict__ b2, const float* __restrict__ bnscale,
    const float* __restrict__ bnshift, float* __restrict__ out)
{
    __shared__ union {
        struct {
            __align__(16) unsigned short As[128][40];
            __align__(16) unsigned short Bs[128][40];
        } s;
        float eps[64][132];
    } u;
    __shared__ float scs[COUT], shs[COUT];
    int pp0 = blockIdx.x * 128;
    int o0  = blockIdx.y * 128;
    int t = threadIdx.x;
    scs[t] = bnscale[t]; shs[t] = bnshift[t];
    int wid = t >> 6, lane = t & 63;
    int wr = wid >> 1, wc = wid & 1;
    int lr = lane & 15, lk = lane >> 4;

    int rowi[2], qi[2];
    ushort8v ra[2], rb[2];
    #pragma unroll
    for (int i = 0; i < 2; ++i) { int id = t + i*256; rowi[i] = id >> 2; qi[i] = id & 3; }
    #pragma unroll
    for (int i = 0; i < 2; ++i) {
        ra[i] = *(const ushort8v*)&W2b[(size_t)(o0 + rowi[i]) * COUT + qi[i]*8];
        rb[i] = *(const ushort8v*)&h1T[(size_t)(pp0 + rowi[i]) * COUT + qi[i]*8];
    }
    f32x4 acc[4][4] = {};
    __syncthreads();

    for (int c0 = 0; c0 < COUT; c0 += 32) {
        #pragma unroll
        for (int i = 0; i < 2; ++i) {
            *(ushort8v*)&u.s.As[rowi[i]][qi[i]*8] = ra[i];
            ushort8v bv;
            #pragma unroll
            for (int j = 0; j < 8; ++j) {
                float f = fmaf(bf2f(rb[i][j]), scs[c0 + qi[i]*8 + j], shs[c0 + qi[i]*8 + j]);
                bv[j] = f2bf(fmaxf(f, 0.0f));
            }
            *(ushort8v*)&u.s.Bs[rowi[i]][qi[i]*8] = bv;
        }
        __syncthreads();
        int cn = (c0 + 32 < COUT) ? c0 + 32 : c0;
        #pragma unroll
        for (int i = 0; i < 2; ++i) {
            ra[i] = *(const ushort8v*)&W2b[(size_t)(o0 + rowi[i]) * COUT + cn + qi[i]*8];
            rb[i] = *(const ushort8v*)&h1T[(size_t)(pp0 + rowi[i]) * COUT + cn + qi[i]*8];
        }
        bf16x8 af[4], bfr[4];
        #pragma unroll
        for (int m = 0; m < 4; ++m) af[m] = *(const bf16x8*)&u.s.As[wr*64 + m*16 + lr][lk*8];
        #pragma unroll
        for (int n = 0; n < 4; ++n) bfr[n] = *(const bf16x8*)&u.s.Bs[wc*64 + n*16 + lr][lk*8];
        #pragma unroll
        for (int m = 0; m < 4; ++m)
            #pragma unroll
            for (int n = 0; n < 4; ++n)
                acc[m][n] = __builtin_amdgcn_mfma_f32_16x16x32_bf16(af[m], bfr[n], acc[m][n], 0, 0, 0);
        __syncthreads();
    }
    // ---- transposed epilogue ----
    int b  = pp0 >> 12;
    int n0 = pp0 & (NN - 1);
    float b2v[4][4];
    #pragma unroll
    for (int m = 0; m < 4; ++m)
        #pragma unroll
        for (int j = 0; j < 4; ++j)
            b2v[m][j] = b2[o0 + wr*64 + m*16 + lk*4 + j];
    #pragma unroll
    for (int ow = 0; ow < 2; ++ow) {
        if (wr == ow) {
            #pragma unroll
            for (int m = 0; m < 4; ++m)
                #pragma unroll
                for (int n = 0; n < 4; ++n) {
                    f32x4 v = acc[m][n];
                    int pl = wc*64 + n*16 + lr;
                    #pragma unroll
                    for (int j = 0; j < 4; ++j)
                        u.eps[m*16 + lk*4 + j][pl] = v[j] + b2v[m][j];
                }
        }
        __syncthreads();
        #pragma unroll
        for (int i = 0; i < 8; ++i) {
            int r  = (t >> 5) + i * 8;
            int c4 = (t & 31) * 4;
            float4 v = *(const float4*)&u.eps[r][c4];
            *(float4*)&out[((size_t)(b * COUT + o0 + ow*64 + r)) * NN + n0 + c4] = v;
        }
        __syncthreads();
    }
}

// ---------------------------------------------------------------------------
extern "C" void kernel_launch(void* const* d_in, const int* in_sizes, int n_in,
                              void* d_out, int out_size, void* d_ws, size_t ws_size,
                              hipStream_t stream)
{
    const float* pts   = (const float*)d_in[0];
    const float* pf    = (const float*)d_in[1];
    const float* cen   = (const float*)d_in[2];
    const float* cf    = (const float*)d_in[3];
    const float* W1    = (const float*)d_in[4];
    const float* b1    = (const float*)d_in[5];
    const float* gamma = (const float*)d_in[6];
    const float* beta  = (const float*)d_in[7];
    const float* W2    = (const float*)d_in[8];
    const float* b2    = (const float*)d_in[9];
    float* out = (float*)d_out;

    char* ws = (char*)d_ws;
    size_t off = 0;
    unsigned short* HbT = (unsigned short*)(ws + off); off += (size_t)NP * KCH * 2;
    unsigned short* h1T = (unsigned short*)(ws + off); off += (size_t)NP * COUT * 2;
    unsigned short* W1b = (unsigned short*)(ws + off); off += (size_t)COUT * KCH * 2;
    unsigned short* W2b = (unsigned short*)(ws + off); off += (size_t)COUT * COUT * 2;
    unsigned short* cfb = (unsigned short*)(ws + off); off += (size_t)BB * MM * CIN * 2;
    float* pdist   = (float*)(ws + off); off += (size_t)NP * NCHUNK * 3 * sizeof(float);
    int*   pidx    = (int*)(ws + off);   off += (size_t)NP * NCHUNK * 3 * sizeof(int);
    float* psum    = (float*)(ws + off); off += (size_t)COUT * NSEG2 * sizeof(float);
    float* psq     = (float*)(ws + off); off += (size_t)COUT * NSEG2 * sizeof(float);
    float* bnscale = (float*)(ws + off); off += 1024;
    float* bnshift = (float*)(ws + off); off += 1024;
    (void)ws_size; (void)in_sizes; (void)n_in; (void)out_size;

    hipLaunchKernelGGL(megak_kernel,  dim3(6784),         dim3(256), 0, stream,
                       pts, cen, pdist, pidx, cf, cfb, pf, HbT, W1, W2, W1b, W2b);
    hipLaunchKernelGGL(interp_kernel, dim3(2048),         dim3(256), 0, stream,
                       cfb, pdist, pidx, HbT);
    hipLaunchKernelGGL(gemm1_kernel,  dim3(NP / 128, 2),  dim3(256), 0, stream,
                       HbT, W1b, b1, h1T, psum, psq);
    hipLaunchKernelGGL(bnfin_kernel,  dim3(COUT),         dim3(256), 0, stream,
                       psum, psq, gamma, beta, bnscale, bnshift);
    hipLaunchKernelGGL(gemm2_kernel,  dim3(NP / 128, 2),  dim3(256), 0, stream,
                       h1T, W2b, b2, bnscale, bnshift, out);
}